// Round 2
// baseline (276.871 us; speedup 1.0000x reference)
//
#include <hip/hip_runtime.h>
#include <hip/hip_bf16.h>
#include <stdint.h>

// ---------------------------------------------------------------------------
// Linformer attention, MI355X (gfx950).
// B=4, S=4096, DM=1024, H=16, DH=64, K=128.
//
// Pipeline (pk = (E*hs)*Wk^T + (sum_s E)*bk^T  -- avoids computing K,V):
//   1. convert hs, Wq, E, D -> fp16; Wk, Wv -> fp16 hi/lo pairs
//   2. rowsum(E), rowsum(D) -> sE, sD  (bias-correction terms)
//   3. Qf   = hs_f16 @ Wq_f16^T + bq               (f32 out)   [16384,1024]
//   4. EHf  = E_f16 @ hs_f16  (per batch, split-K atomics)     [512,1024] f32
//      DHf  = D_f16 @ hs_f16
//   5. pkf  = split(EHf) @ (WkH,WkL)^T + sE*bk     (f32)       [512,1024]
//      pvf  = split(DHf) @ (WvH,WvL)^T + sD*bv
//   6. fused attention: scores = split(q) @ split(pk)^T /8, softmax(128),
//      ctx = P @ f16(pv)   -> out f32 [4,4096,1024]
//
// Precision: fp16 (unit roundoff 2^-11, 8x better than bf16) everywhere,
// f32 MFMA accumulation; hi/lo 3-term splits on the score-critical paths.
// ---------------------------------------------------------------------------

typedef __attribute__((ext_vector_type(8))) _Float16 f16x8;   // 4 VGPR
typedef __attribute__((ext_vector_type(4))) _Float16 f16x4;
typedef __attribute__((ext_vector_type(4))) float    f32x4;

__device__ __forceinline__ f32x4 mfma16(f16x8 a, f16x8 b, f32x4 c) {
    return __builtin_amdgcn_mfma_f32_16x16x32_f16(a, b, c, 0, 0, 0);
}

// ---------------------------------------------------------------- converts --
__global__ __launch_bounds__(256) void cvt_f16(const float* __restrict__ in,
                                               _Float16* __restrict__ out, int n4) {
    int i = blockIdx.x * 256 + threadIdx.x;
    int stride = gridDim.x * 256;
    for (; i < n4; i += stride) {
        f32x4 v = reinterpret_cast<const f32x4*>(in)[i];
        f16x4 o;
#pragma unroll
        for (int j = 0; j < 4; ++j) o[j] = (_Float16)v[j];
        reinterpret_cast<f16x4*>(out)[i] = o;
    }
}

__global__ __launch_bounds__(256) void cvt_hilo(const float* __restrict__ in,
                                                _Float16* __restrict__ hi,
                                                _Float16* __restrict__ lo, int n4) {
    int i = blockIdx.x * 256 + threadIdx.x;
    int stride = gridDim.x * 256;
    for (; i < n4; i += stride) {
        f32x4 v = reinterpret_cast<const f32x4*>(in)[i];
        f16x4 h, l;
#pragma unroll
        for (int j = 0; j < 4; ++j) {
            _Float16 hb = (_Float16)v[j];
            h[j] = hb;
            l[j] = (_Float16)(v[j] - (float)hb);
        }
        reinterpret_cast<f16x4*>(hi)[i] = h;
        reinterpret_cast<f16x4*>(lo)[i] = l;
    }
}

// rowsum over S=4096 for E and D: blocks 0..127 -> E rows, 128..255 -> D rows
__global__ __launch_bounds__(256) void rowsum_k(const float* __restrict__ E,
                                                const float* __restrict__ D,
                                                float* __restrict__ sE,
                                                float* __restrict__ sD) {
    __shared__ float red[256];
    const int blk = blockIdx.x;
    const float* src = (blk < 128) ? E : D;
    float* dst = (blk < 128) ? sE : sD;
    const int row = blk & 127;
    float s = 0.f;
    for (int i = threadIdx.x; i < 4096; i += 256) s += src[(size_t)row * 4096 + i];
    red[threadIdx.x] = s;
    __syncthreads();
    for (int off = 128; off > 0; off >>= 1) {
        if ((int)threadIdx.x < off) red[threadIdx.x] += red[threadIdx.x + off];
        __syncthreads();
    }
    if (threadIdx.x == 0) dst[row] = red[0];
}

// ------------------------------------------------------- NT GEMM (Q proj) --
// C[M,N] f32 = A[M,K]f16 * B[N,K]f16^T + bias[N].  128x128 tile, BK=64.
__global__ __launch_bounds__(256) void gemm_nt_bias_f32(
    const _Float16* __restrict__ A, const _Float16* __restrict__ B,
    const float* __restrict__ bias, float* __restrict__ C,
    int M, int N, int Kd) {
    __shared__ _Float16 Asm[128 * 72];
    __shared__ _Float16 Bsm[128 * 72];
    const int tid = threadIdx.x, lane = tid & 63, wave = tid >> 6;
    const int l15 = lane & 15, lg = lane >> 4;
    const int row0 = blockIdx.x * 128, col0 = blockIdx.y * 128;
    const int wr = (wave >> 1) * 64, wc = (wave & 1) * 64;
    f32x4 acc[4][4];
#pragma unroll
    for (int m = 0; m < 4; ++m)
#pragma unroll
        for (int n = 0; n < 4; ++n) acc[m][n] = (f32x4)0.0f;

    for (int k0 = 0; k0 < Kd; k0 += 64) {
        __syncthreads();
#pragma unroll
        for (int i = 0; i < 4; ++i) {
            int u = tid + 256 * i;
            int r = u >> 3, c8 = (u & 7) * 8;
            *reinterpret_cast<f16x8*>(&Asm[r * 72 + c8]) =
                *reinterpret_cast<const f16x8*>(A + (size_t)(row0 + r) * Kd + k0 + c8);
            *reinterpret_cast<f16x8*>(&Bsm[r * 72 + c8]) =
                *reinterpret_cast<const f16x8*>(B + (size_t)(col0 + r) * Kd + k0 + c8);
        }
        __syncthreads();
#pragma unroll
        for (int kk = 0; kk < 2; ++kk) {
            f16x8 af[4], bfr[4];
#pragma unroll
            for (int m = 0; m < 4; ++m)
                af[m] = *reinterpret_cast<const f16x8*>(
                    &Asm[(wr + m * 16 + l15) * 72 + kk * 32 + lg * 8]);
#pragma unroll
            for (int n = 0; n < 4; ++n)
                bfr[n] = *reinterpret_cast<const f16x8*>(
                    &Bsm[(wc + n * 16 + l15) * 72 + kk * 32 + lg * 8]);
#pragma unroll
            for (int m = 0; m < 4; ++m)
#pragma unroll
                for (int n = 0; n < 4; ++n) acc[m][n] = mfma16(af[m], bfr[n], acc[m][n]);
        }
    }
#pragma unroll
    for (int m = 0; m < 4; ++m)
#pragma unroll
        for (int n = 0; n < 4; ++n) {
            int colg = col0 + wc + n * 16 + l15;
            float bi = bias[colg];
#pragma unroll
            for (int r = 0; r < 4; ++r) {
                int rowg = row0 + wr + m * 16 + lg * 4 + r;
                C[(size_t)rowg * N + colg] = acc[m][n][r] + bi;
            }
        }
}

// -------------------------------------------- E/D @ hs projection (NN GEMM) --
// Of[b*128+kk, n] += sum_s Emat[kk,s]*X[b*4096+s, n]; split-K over blockIdx.x.
__global__ __launch_bounds__(256) void eproj(const _Float16* __restrict__ Emat,
                                             const _Float16* __restrict__ X,
                                             float* __restrict__ Of) {
    __shared__ _Float16 Ea[128 * 72];
    __shared__ _Float16 BT[128 * 72];
    const int tid = threadIdx.x, lane = tid & 63, wave = tid >> 6;
    const int l15 = lane & 15, lg = lane >> 4;
    const int sc = blockIdx.x;          // K-chunk 0..7 (512 rows each)
    const int n0 = blockIdx.y * 128;
    const int bb = blockIdx.z;
    const int wr = (wave >> 1) * 64, wc = (wave & 1) * 64;
    const int nb = tid & 31, sb = tid >> 5;
    f32x4 acc[4][4];
#pragma unroll
    for (int m = 0; m < 4; ++m)
#pragma unroll
        for (int n = 0; n < 4; ++n) acc[m][n] = (f32x4)0.0f;

    for (int ks = 0; ks < 512; ks += 64) {
        const int s0 = sc * 512 + ks;
        __syncthreads();
#pragma unroll
        for (int i = 0; i < 4; ++i) {  // A tile: E [128 kk][64 s]
            int u = tid + 256 * i;
            int r = u >> 3, c8 = (u & 7) * 8;
            *reinterpret_cast<f16x8*>(&Ea[r * 72 + c8]) =
                *reinterpret_cast<const f16x8*>(Emat + (size_t)r * 4096 + s0 + c8);
        }
        {   // B tile: X [64 s][128 n] -> transposed BT[n][s]
            f16x4 rr[8];
#pragma unroll
            for (int i = 0; i < 8; ++i)
                rr[i] = *reinterpret_cast<const f16x4*>(
                    X + (size_t)(bb * 4096 + s0 + sb * 8 + i) * 1024 + n0 + nb * 4);
#pragma unroll
            for (int j = 0; j < 4; ++j) {
                f16x8 w;
#pragma unroll
                for (int i = 0; i < 8; ++i) w[i] = rr[i][j];
                *reinterpret_cast<f16x8*>(&BT[(nb * 4 + j) * 72 + sb * 8]) = w;
            }
        }
        __syncthreads();
#pragma unroll
        for (int kk = 0; kk < 2; ++kk) {
            f16x8 af[4], bfr[4];
#pragma unroll
            for (int m = 0; m < 4; ++m)
                af[m] = *reinterpret_cast<const f16x8*>(
                    &Ea[(wr + m * 16 + l15) * 72 + kk * 32 + lg * 8]);
#pragma unroll
            for (int n = 0; n < 4; ++n)
                bfr[n] = *reinterpret_cast<const f16x8*>(
                    &BT[(wc + n * 16 + l15) * 72 + kk * 32 + lg * 8]);
#pragma unroll
            for (int m = 0; m < 4; ++m)
#pragma unroll
                for (int n = 0; n < 4; ++n) acc[m][n] = mfma16(af[m], bfr[n], acc[m][n]);
        }
    }
#pragma unroll
    for (int m = 0; m < 4; ++m)
#pragma unroll
        for (int n = 0; n < 4; ++n)
#pragma unroll
            for (int r = 0; r < 4; ++r)
                atomicAdd(&Of[(size_t)(bb * 128 + wr + m * 16 + lg * 4 + r) * 1024 +
                              n0 + wc + n * 16 + l15],
                          acc[m][n][r]);
}

// ----------------------------- split-precision NT GEMM (pk / pv, tiny M) --
// C f32 = split(A f32) @ (Bh+Bl)^T + rowscale[row%128]*bias[col].  BK=32.
__global__ __launch_bounds__(256) void gemm_split_nt(
    const float* __restrict__ A, const _Float16* __restrict__ Bh,
    const _Float16* __restrict__ Bl, const float* __restrict__ bias,
    const float* __restrict__ rowscale, float* __restrict__ C,
    int M, int N, int Kd) {
    __shared__ _Float16 Ah[128 * 40], Al[128 * 40], Bhs[128 * 40], Bls[128 * 40];
    const int tid = threadIdx.x, lane = tid & 63, wave = tid >> 6;
    const int l15 = lane & 15, lg = lane >> 4;
    const int row0 = blockIdx.x * 128, col0 = blockIdx.y * 128;
    const int wr = (wave >> 1) * 64, wc = (wave & 1) * 64;
    f32x4 acc[4][4];
#pragma unroll
    for (int m = 0; m < 4; ++m)
#pragma unroll
        for (int n = 0; n < 4; ++n) acc[m][n] = (f32x4)0.0f;

    for (int k0 = 0; k0 < Kd; k0 += 32) {
        __syncthreads();
#pragma unroll
        for (int i = 0; i < 2; ++i) {
            int u = tid + 256 * i;
            int r = u >> 2, c8 = (u & 3) * 8;
            const float* src = A + (size_t)(row0 + r) * Kd + k0 + c8;
            f32x4 v0 = *reinterpret_cast<const f32x4*>(src);
            f32x4 v1 = *reinterpret_cast<const f32x4*>(src + 4);
            f16x8 h8, l8;
#pragma unroll
            for (int j = 0; j < 4; ++j) {
                _Float16 hb = (_Float16)v0[j];
                h8[j] = hb; l8[j] = (_Float16)(v0[j] - (float)hb);
            }
#pragma unroll
            for (int j = 0; j < 4; ++j) {
                _Float16 hb = (_Float16)v1[j];
                h8[4 + j] = hb; l8[4 + j] = (_Float16)(v1[j] - (float)hb);
            }
            *reinterpret_cast<f16x8*>(&Ah[r * 40 + c8]) = h8;
            *reinterpret_cast<f16x8*>(&Al[r * 40 + c8]) = l8;
            *reinterpret_cast<f16x8*>(&Bhs[r * 40 + c8]) =
                *reinterpret_cast<const f16x8*>(Bh + (size_t)(col0 + r) * Kd + k0 + c8);
            *reinterpret_cast<f16x8*>(&Bls[r * 40 + c8]) =
                *reinterpret_cast<const f16x8*>(Bl + (size_t)(col0 + r) * Kd + k0 + c8);
        }
        __syncthreads();
        f16x8 ah[4], al[4], bh[4], bl[4];
#pragma unroll
        for (int m = 0; m < 4; ++m) {
            ah[m] = *reinterpret_cast<const f16x8*>(&Ah[(wr + m * 16 + l15) * 40 + lg * 8]);
            al[m] = *reinterpret_cast<const f16x8*>(&Al[(wr + m * 16 + l15) * 40 + lg * 8]);
        }
#pragma unroll
        for (int n = 0; n < 4; ++n) {
            bh[n] = *reinterpret_cast<const f16x8*>(&Bhs[(wc + n * 16 + l15) * 40 + lg * 8]);
            bl[n] = *reinterpret_cast<const f16x8*>(&Bls[(wc + n * 16 + l15) * 40 + lg * 8]);
        }
#pragma unroll
        for (int m = 0; m < 4; ++m)
#pragma unroll
            for (int n = 0; n < 4; ++n) {
                acc[m][n] = mfma16(ah[m], bh[n], acc[m][n]);
                acc[m][n] = mfma16(al[m], bh[n], acc[m][n]);
                acc[m][n] = mfma16(ah[m], bl[n], acc[m][n]);
            }
    }
#pragma unroll
    for (int m = 0; m < 4; ++m)
#pragma unroll
        for (int n = 0; n < 4; ++n) {
            int colg = col0 + wc + n * 16 + l15;
            float bi = bias[colg];
#pragma unroll
            for (int r = 0; r < 4; ++r) {
                int rowg = row0 + wr + m * 16 + lg * 4 + r;
                C[(size_t)rowg * N + colg] = acc[m][n][r] + rowscale[rowg & 127] * bi;
            }
        }
}

// ------------------------------------------------------- fused attention --
// Per block: (b, h, 128 q-rows). scores = split(q)@split(pk)^T /8 -> softmax
// over 128 -> P @ f16(pv) -> out.  4 waves x 32 rows.
__global__ __launch_bounds__(256) void attn_fused(
    const float* __restrict__ Qf, const float* __restrict__ PK,
    const float* __restrict__ PV, float* __restrict__ Out) {
    // pk hi/lo [128][72] each; pvT [64][136]; P aliases the pk region.
    __shared__ _Float16 smem[128 * 72 * 2 + 64 * 136];
    _Float16* pkh = smem;
    _Float16* pkl = smem + 128 * 72;
    _Float16* pvt = smem + 2 * 128 * 72;
    _Float16* plds = smem;  // alias (after barrier)

    const int tid = threadIdx.x, lane = tid & 63, wave = tid >> 6;
    const int l15 = lane & 15, lg = lane >> 4;
    const int st = blockIdx.x, h = blockIdx.y, bb = blockIdx.z;

    // stage pk -> hi/lo f16
#pragma unroll
    for (int i = 0; i < 4; ++i) {
        int u = tid + 256 * i;
        int r = u >> 3, c8 = (u & 7) * 8;
        const float* src = PK + (size_t)(bb * 128 + r) * 1024 + h * 64 + c8;
        f32x4 v0 = *reinterpret_cast<const f32x4*>(src);
        f32x4 v1 = *reinterpret_cast<const f32x4*>(src + 4);
        f16x8 h8, l8;
#pragma unroll
        for (int j = 0; j < 4; ++j) {
            _Float16 hb = (_Float16)v0[j];
            h8[j] = hb; l8[j] = (_Float16)(v0[j] - (float)hb);
        }
#pragma unroll
        for (int j = 0; j < 4; ++j) {
            _Float16 hb = (_Float16)v1[j];
            h8[4 + j] = hb; l8[4 + j] = (_Float16)(v1[j] - (float)hb);
        }
        *reinterpret_cast<f16x8*>(&pkh[r * 72 + c8]) = h8;
        *reinterpret_cast<f16x8*>(&pkl[r * 72 + c8]) = l8;
    }
    // stage pv transposed: pvT[d][k]
    {
        const int db = tid & 15, kb = tid >> 4;
        f32x4 f[8];
#pragma unroll
        for (int i = 0; i < 8; ++i)
            f[i] = *reinterpret_cast<const f32x4*>(
                PV + (size_t)(bb * 128 + kb * 8 + i) * 1024 + h * 64 + db * 4);
#pragma unroll
        for (int j = 0; j < 4; ++j) {
            f16x8 w;
#pragma unroll
            for (int i = 0; i < 8; ++i) w[i] = (_Float16)f[i][j];
            *reinterpret_cast<f16x8*>(&pvt[(db * 4 + j) * 136 + kb * 8]) = w;
        }
    }
    // q fragments (hi/lo split, direct from global f32)
    const int srow0 = bb * 4096 + st * 128 + wave * 32;
    f16x8 qh[2][2], ql[2][2];
#pragma unroll
    for (int m = 0; m < 2; ++m)
#pragma unroll
        for (int kk = 0; kk < 2; ++kk) {
            const float* src =
                Qf + (size_t)(srow0 + m * 16 + l15) * 1024 + h * 64 + kk * 32 + lg * 8;
            f32x4 v0 = *reinterpret_cast<const f32x4*>(src);
            f32x4 v1 = *reinterpret_cast<const f32x4*>(src + 4);
            f16x8 hh, ll;
#pragma unroll
            for (int j = 0; j < 4; ++j) {
                _Float16 hb = (_Float16)v0[j];
                hh[j] = hb; ll[j] = (_Float16)(v0[j] - (float)hb);
            }
#pragma unroll
            for (int j = 0; j < 4; ++j) {
                _Float16 hb = (_Float16)v1[j];
                hh[4 + j] = hb; ll[4 + j] = (_Float16)(v1[j] - (float)hb);
            }
            qh[m][kk] = hh;
            ql[m][kk] = ll;
        }
    __syncthreads();

    // scores: acc[m][n] over K=64 (2 kk), 3-term split
    f32x4 acc[2][8];
#pragma unroll
    for (int m = 0; m < 2; ++m)
#pragma unroll
        for (int n = 0; n < 8; ++n) acc[m][n] = (f32x4)0.0f;
#pragma unroll
    for (int kk = 0; kk < 2; ++kk)
#pragma unroll
        for (int n = 0; n < 8; ++n) {
            f16x8 bh = *reinterpret_cast<const f16x8*>(
                &pkh[(n * 16 + l15) * 72 + kk * 32 + lg * 8]);
            f16x8 bl = *reinterpret_cast<const f16x8*>(
                &pkl[(n * 16 + l15) * 72 + kk * 32 + lg * 8]);
#pragma unroll
            for (int m = 0; m < 2; ++m) {
                acc[m][n] = mfma16(qh[m][kk], bh, acc[m][n]);
                acc[m][n] = mfma16(ql[m][kk], bh, acc[m][n]);
                acc[m][n] = mfma16(qh[m][kk], bl, acc[m][n]);
            }
        }

    // softmax over the 128 cols (8 n-frags x 16 lanes), deferred 1/denom
    float mx[2][4], inv[2][4];
#pragma unroll
    for (int m = 0; m < 2; ++m)
#pragma unroll
        for (int r = 0; r < 4; ++r) {
            float v = -1e30f;
#pragma unroll
            for (int n = 0; n < 8; ++n) v = fmaxf(v, acc[m][n][r]);
#pragma unroll
            for (int msk = 1; msk < 16; msk <<= 1) v = fmaxf(v, __shfl_xor(v, msk));
            mx[m][r] = v * 0.125f;
        }
#pragma unroll
    for (int m = 0; m < 2; ++m)
#pragma unroll
        for (int n = 0; n < 8; ++n)
#pragma unroll
            for (int r = 0; r < 4; ++r)
                acc[m][n][r] = __expf(acc[m][n][r] * 0.125f - mx[m][r]);
#pragma unroll
    for (int m = 0; m < 2; ++m)
#pragma unroll
        for (int r = 0; r < 4; ++r) {
            float s = 0.f;
#pragma unroll
            for (int n = 0; n < 8; ++n) s += acc[m][n][r];
#pragma unroll
            for (int msk = 1; msk < 16; msk <<= 1) s += __shfl_xor(s, msk);
            inv[m][r] = 1.0f / s;
        }
    __syncthreads();  // everyone done reading pk: safe to alias P over it

    _Float16* pw = plds + wave * (32 * 136);
#pragma unroll
    for (int m = 0; m < 2; ++m)
#pragma unroll
        for (int n = 0; n < 8; ++n)
#pragma unroll
            for (int r = 0; r < 4; ++r)
                pw[(m * 16 + lg * 4 + r) * 136 + n * 16 + l15] = (_Float16)acc[m][n][r];
    __syncthreads();

    // PV: ctx[32 rows x 64 d] per wave, K=128 (4 ksteps)
    f32x4 o[2][4];
#pragma unroll
    for (int m = 0; m < 2; ++m)
#pragma unroll
        for (int n = 0; n < 4; ++n) o[m][n] = (f32x4)0.0f;
#pragma unroll
    for (int ks = 0; ks < 4; ++ks) {
        f16x8 af[2];
#pragma unroll
        for (int m = 0; m < 2; ++m)
            af[m] = *reinterpret_cast<const f16x8*>(
                &pw[(m * 16 + l15) * 136 + ks * 32 + lg * 8]);
#pragma unroll
        for (int n = 0; n < 4; ++n) {
            f16x8 bfr = *reinterpret_cast<const f16x8*>(
                &pvt[(n * 16 + l15) * 136 + ks * 32 + lg * 8]);
#pragma unroll
            for (int m = 0; m < 2; ++m) o[m][n] = mfma16(af[m], bfr, o[m][n]);
        }
    }
#pragma unroll
    for (int m = 0; m < 2; ++m)
#pragma unroll
        for (int n = 0; n < 4; ++n)
#pragma unroll
            for (int r = 0; r < 4; ++r) {
                int row = srow0 + m * 16 + lg * 4 + r;
                Out[(size_t)row * 1024 + h * 64 + n * 16 + l15] = o[m][n][r] * inv[m][r];
            }
}

// ---------------------------------------------------------------------------
extern "C" void kernel_launch(void* const* d_in, const int* in_sizes, int n_in,
                              void* d_out, int out_size, void* d_ws, size_t ws_size,
                              hipStream_t stream) {
    const float* hs = (const float*)d_in[0];
    const float* Wq = (const float*)d_in[1];
    const float* bq = (const float*)d_in[2];
    const float* Wk = (const float*)d_in[3];
    const float* bk = (const float*)d_in[4];
    const float* Wv = (const float*)d_in[5];
    const float* bv = (const float*)d_in[6];
    const float* Em = (const float*)d_in[7];
    const float* Dm = (const float*)d_in[8];
    float* out = (float*)d_out;
    char* ws = (char*)d_ws;

    // workspace layout (bytes)
    _Float16* hsB = (_Float16*)(ws + 0);                  // 33,554,432
    _Float16* WqB = (_Float16*)(ws + 33554432);           //  2,097,152
    _Float16* WkH = (_Float16*)(ws + 35651584);
    _Float16* WkL = (_Float16*)(ws + 37748736);
    _Float16* WvH = (_Float16*)(ws + 39845888);
    _Float16* WvL = (_Float16*)(ws + 41943040);
    _Float16* EB  = (_Float16*)(ws + 44040192);           //  1,048,576
    _Float16* DB  = (_Float16*)(ws + 45088768);
    float* sE  = (float*)(ws + 46137344);                 //        512
    float* sD  = (float*)(ws + 46137856);
    float* Qf  = (float*)(ws + 46138368);                 // 67,108,864
    float* EHf = (float*)(ws + 113247232);                //  2,097,152
    float* DHf = (float*)(ws + 115344384);
    float* pkf = (float*)(ws + 117441536);
    float* pvf = (float*)(ws + 119538688);                // end 121,635,840

    // 1. dtype converts
    cvt_f16<<<2048, 256, 0, stream>>>(hs, hsB, 16777216 / 4);
    cvt_f16<<<1024, 256, 0, stream>>>(Wq, WqB, 1048576 / 4);
    cvt_hilo<<<1024, 256, 0, stream>>>(Wk, WkH, WkL, 1048576 / 4);
    cvt_hilo<<<1024, 256, 0, stream>>>(Wv, WvH, WvL, 1048576 / 4);
    cvt_f16<<<512, 256, 0, stream>>>(Em, EB, 524288 / 4);
    cvt_f16<<<512, 256, 0, stream>>>(Dm, DB, 524288 / 4);
    // 2. bias-correction row sums
    rowsum_k<<<256, 256, 0, stream>>>(Em, Dm, sE, sD);
    // 3. Q projection
    gemm_nt_bias_f32<<<dim3(128, 8), 256, 0, stream>>>(hsB, WqB, bq, Qf,
                                                       16384, 1024, 1024);
    // 4. EH = E @ hs, DH = D @ hs (split-K atomics)
    hipMemsetAsync(EHf, 0, 2 * 512 * 1024 * sizeof(float), stream);
    eproj<<<dim3(8, 8, 4), 256, 0, stream>>>(EB, hsB, EHf);
    eproj<<<dim3(8, 8, 4), 256, 0, stream>>>(DB, hsB, DHf);
    // 5. pk = EH @ Wk^T + sE*bk ; pv = DH @ Wv^T + sD*bv
    gemm_split_nt<<<dim3(4, 8), 256, 0, stream>>>(EHf, WkH, WkL, bk, sE, pkf,
                                                  512, 1024, 1024);
    gemm_split_nt<<<dim3(4, 8), 256, 0, stream>>>(DHf, WvH, WvL, bv, sD, pvf,
                                                  512, 1024, 1024);
    // 6. fused attention
    attn_fused<<<dim3(32, 16, 4), 256, 0, stream>>>(Qf, pkf, pvf, out);
}

// Round 3
// 206.371 us; speedup vs baseline: 1.3416x; 1.3416x over previous
//
#include <hip/hip_runtime.h>
#include <hip/hip_bf16.h>
#include <stdint.h>

// ---------------------------------------------------------------------------
// Linformer attention, MI355X (gfx950).
// B=4, S=4096, DM=1024, H=16, DH=64, K=128.
//
// Pipeline (pk = (E*hs)*Wk^T + (sum_s E)*bk^T  -- avoids computing K,V):
//   1. convert hs, Wq, E, D -> fp16; Wk, Wv -> fp16 hi/lo pairs
//   2. rowsum(E), rowsum(D) -> sE, sD  (bias-correction terms)
//   3. Qf   = hs_f16 @ Wq_f16^T + bq    (f32, global_load_lds+swizzle GEMM)
//   4. EHf  = E_f16 @ hs_f16  (split-K atomics, E and D in one launch)
//   5. pkf/pvf = split(EHf/DHf) @ (Wh,Wl)^T + s*b  (one launch)
//   6. prep_attn: pkf -> PKH/PKL f16 (same layout); pvf -> PVT f16 [bh][d][k]
//   7. attn: gload_lds-staged pk hi/lo + pvT (XOR-swizzled), 3-term scores,
//      wave-local softmax, P aliased over pk LDS (swizzled), PV, out f32.
// ---------------------------------------------------------------------------

typedef __attribute__((ext_vector_type(8))) _Float16 f16x8;   // 4 VGPR
typedef __attribute__((ext_vector_type(4))) _Float16 f16x4;
typedef __attribute__((ext_vector_type(4))) float    f32x4;

__device__ __forceinline__ f32x4 mfma16(f16x8 a, f16x8 b, f32x4 c) {
    return __builtin_amdgcn_mfma_f32_16x16x32_f16(a, b, c, 0, 0, 0);
}

// async global->LDS, 16B per lane; LDS dest = wave-uniform base + lane*16
__device__ __forceinline__ void gload16(const void* g, void* l) {
    __builtin_amdgcn_global_load_lds(
        (const __attribute__((address_space(1))) void*)g,
        (__attribute__((address_space(3))) void*)l, 16, 0, 0);
}

// ---------------------------------------------------------------- converts --
__global__ __launch_bounds__(256) void cvt_f16(const float* __restrict__ in,
                                               _Float16* __restrict__ out, int n4) {
    int i = blockIdx.x * 256 + threadIdx.x;
    int stride = gridDim.x * 256;
    for (; i < n4; i += stride) {
        f32x4 v = reinterpret_cast<const f32x4*>(in)[i];
        f16x4 o;
#pragma unroll
        for (int j = 0; j < 4; ++j) o[j] = (_Float16)v[j];
        reinterpret_cast<f16x4*>(out)[i] = o;
    }
}

__global__ __launch_bounds__(256) void cvt_f16_2(const float* __restrict__ in0,
                                                 _Float16* __restrict__ out0,
                                                 const float* __restrict__ in1,
                                                 _Float16* __restrict__ out1, int n4) {
    const float* in = blockIdx.y ? in1 : in0;
    _Float16* out = blockIdx.y ? out1 : out0;
    int i = blockIdx.x * 256 + threadIdx.x;
    int stride = gridDim.x * 256;
    for (; i < n4; i += stride) {
        f32x4 v = reinterpret_cast<const f32x4*>(in)[i];
        f16x4 o;
#pragma unroll
        for (int j = 0; j < 4; ++j) o[j] = (_Float16)v[j];
        reinterpret_cast<f16x4*>(out)[i] = o;
    }
}

__global__ __launch_bounds__(256) void cvt_hilo2(const float* __restrict__ in0,
                                                 _Float16* __restrict__ hi0,
                                                 _Float16* __restrict__ lo0,
                                                 const float* __restrict__ in1,
                                                 _Float16* __restrict__ hi1,
                                                 _Float16* __restrict__ lo1, int n4) {
    const float* in = blockIdx.y ? in1 : in0;
    _Float16* hi = blockIdx.y ? hi1 : hi0;
    _Float16* lo = blockIdx.y ? lo1 : lo0;
    int i = blockIdx.x * 256 + threadIdx.x;
    int stride = gridDim.x * 256;
    for (; i < n4; i += stride) {
        f32x4 v = reinterpret_cast<const f32x4*>(in)[i];
        f16x4 h, l;
#pragma unroll
        for (int j = 0; j < 4; ++j) {
            _Float16 hb = (_Float16)v[j];
            h[j] = hb;
            l[j] = (_Float16)(v[j] - (float)hb);
        }
        reinterpret_cast<f16x4*>(hi)[i] = h;
        reinterpret_cast<f16x4*>(lo)[i] = l;
    }
}

// rowsum over S=4096 for E and D: blocks 0..127 -> E rows, 128..255 -> D rows
__global__ __launch_bounds__(256) void rowsum_k(const float* __restrict__ E,
                                                const float* __restrict__ D,
                                                float* __restrict__ sE,
                                                float* __restrict__ sD) {
    __shared__ float red[256];
    const int blk = blockIdx.x;
    const float* src = (blk < 128) ? E : D;
    float* dst = (blk < 128) ? sE : sD;
    const int row = blk & 127;
    float s = 0.f;
    for (int i = threadIdx.x; i < 4096; i += 256) s += src[(size_t)row * 4096 + i];
    red[threadIdx.x] = s;
    __syncthreads();
    for (int off = 128; off > 0; off >>= 1) {
        if ((int)threadIdx.x < off) red[threadIdx.x] += red[threadIdx.x + off];
        __syncthreads();
    }
    if (threadIdx.x == 0) dst[row] = red[0];
}

// ------------------------------------------------------- NT GEMM (Q proj) --
// C[M,N] f32 = A[M,K]f16 * B[N,K]f16^T + bias[N].  128x128 tile, BK=64,
// global_load_lds staging with chunk-XOR swizzle (linear LDS).
__global__ __launch_bounds__(256) void gemm_nt_bias_f32(
    const _Float16* __restrict__ A, const _Float16* __restrict__ B,
    const float* __restrict__ bias, float* __restrict__ C,
    int M, int N, int Kd) {
    __shared__ _Float16 Asm[128 * 64];
    __shared__ _Float16 Bsm[128 * 64];
    const int tid = threadIdx.x, lane = tid & 63, wave = tid >> 6;
    const int l15 = lane & 15, lg = lane >> 4;
    const int row0 = blockIdx.x * 128, col0 = blockIdx.y * 128;
    const int wr = (wave >> 1) * 64, wc = (wave & 1) * 64;
    f32x4 acc[4][4];
#pragma unroll
    for (int m = 0; m < 4; ++m)
#pragma unroll
        for (int n = 0; n < 4; ++n) acc[m][n] = (f32x4)0.0f;

    // per-lane swizzled source chunk: slot u=(r,c) holds global chunk c^(r&7)
    const int su = wave * 64 + lane;            // slot within a 256-slot batch
    for (int k0 = 0; k0 < Kd; k0 += 64) {
        __syncthreads();
#pragma unroll
        for (int it = 0; it < 4; ++it) {
            int u = it * 256 + su;
            int r = u >> 3, c = u & 7;
            int sc = (c ^ (r & 7)) * 8;
            int ub = it * 256 + wave * 64;      // wave-uniform LDS slot base
            gload16(A + (size_t)(row0 + r) * Kd + k0 + sc, &Asm[ub * 8]);
            gload16(B + (size_t)(col0 + r) * Kd + k0 + sc, &Bsm[ub * 8]);
        }
        __syncthreads();
#pragma unroll
        for (int kk = 0; kk < 2; ++kk) {
            f16x8 af[4], bfr[4];
#pragma unroll
            for (int m = 0; m < 4; ++m)
                af[m] = *reinterpret_cast<const f16x8*>(
                    &Asm[(wr + m * 16 + l15) * 64 + (((kk * 4 + lg) ^ (l15 & 7)) * 8)]);
#pragma unroll
            for (int n = 0; n < 4; ++n)
                bfr[n] = *reinterpret_cast<const f16x8*>(
                    &Bsm[(wc + n * 16 + l15) * 64 + (((kk * 4 + lg) ^ (l15 & 7)) * 8)]);
#pragma unroll
            for (int m = 0; m < 4; ++m)
#pragma unroll
                for (int n = 0; n < 4; ++n) acc[m][n] = mfma16(af[m], bfr[n], acc[m][n]);
        }
    }
#pragma unroll
    for (int m = 0; m < 4; ++m)
#pragma unroll
        for (int n = 0; n < 4; ++n) {
            int colg = col0 + wc + n * 16 + l15;
            float bi = bias[colg];
#pragma unroll
            for (int r = 0; r < 4; ++r) {
                int rowg = row0 + wr + m * 16 + lg * 4 + r;
                C[(size_t)rowg * N + colg] = acc[m][n][r] + bi;
            }
        }
}

// -------------------------------------------- E/D @ hs projection (NN GEMM) --
// Of[b*128+kk, n] += sum_s Emat[kk,s]*X[b*4096+s, n]; split-K over blockIdx.x.
// blockIdx.z: 0..3 -> E batches, 4..7 -> D batches.
__global__ __launch_bounds__(256) void eproj2(const _Float16* __restrict__ EB,
                                              const _Float16* __restrict__ DB,
                                              const _Float16* __restrict__ X,
                                              float* __restrict__ EHf,
                                              float* __restrict__ DHf) {
    __shared__ _Float16 Ea[128 * 72];
    __shared__ _Float16 BT[128 * 72];
    const int tid = threadIdx.x, lane = tid & 63, wave = tid >> 6;
    const int l15 = lane & 15, lg = lane >> 4;
    const int sc = blockIdx.x;          // K-chunk 0..7 (512 rows each)
    const int n0 = blockIdx.y * 128;
    const int bb = blockIdx.z & 3;
    const _Float16* Emat = (blockIdx.z >> 2) ? DB : EB;
    float* Of = (blockIdx.z >> 2) ? DHf : EHf;
    const int wr = (wave >> 1) * 64, wc = (wave & 1) * 64;
    const int nb = tid & 31, sb = tid >> 5;
    f32x4 acc[4][4];
#pragma unroll
    for (int m = 0; m < 4; ++m)
#pragma unroll
        for (int n = 0; n < 4; ++n) acc[m][n] = (f32x4)0.0f;

    for (int ks = 0; ks < 512; ks += 64) {
        const int s0 = sc * 512 + ks;
        __syncthreads();
#pragma unroll
        for (int i = 0; i < 4; ++i) {  // A tile: E [128 kk][64 s]
            int u = tid + 256 * i;
            int r = u >> 3, c8 = (u & 7) * 8;
            *reinterpret_cast<f16x8*>(&Ea[r * 72 + c8]) =
                *reinterpret_cast<const f16x8*>(Emat + (size_t)r * 4096 + s0 + c8);
        }
        {   // B tile: X [64 s][128 n] -> transposed BT[n][s]
            f16x4 rr[8];
#pragma unroll
            for (int i = 0; i < 8; ++i)
                rr[i] = *reinterpret_cast<const f16x4*>(
                    X + (size_t)(bb * 4096 + s0 + sb * 8 + i) * 1024 + n0 + nb * 4);
#pragma unroll
            for (int j = 0; j < 4; ++j) {
                f16x8 w;
#pragma unroll
                for (int i = 0; i < 8; ++i) w[i] = rr[i][j];
                *reinterpret_cast<f16x8*>(&BT[(nb * 4 + j) * 72 + sb * 8]) = w;
            }
        }
        __syncthreads();
#pragma unroll
        for (int kk = 0; kk < 2; ++kk) {
            f16x8 af[4], bfr[4];
#pragma unroll
            for (int m = 0; m < 4; ++m)
                af[m] = *reinterpret_cast<const f16x8*>(
                    &Ea[(wr + m * 16 + l15) * 72 + kk * 32 + lg * 8]);
#pragma unroll
            for (int n = 0; n < 4; ++n)
                bfr[n] = *reinterpret_cast<const f16x8*>(
                    &BT[(wc + n * 16 + l15) * 72 + kk * 32 + lg * 8]);
#pragma unroll
            for (int m = 0; m < 4; ++m)
#pragma unroll
                for (int n = 0; n < 4; ++n) acc[m][n] = mfma16(af[m], bfr[n], acc[m][n]);
        }
    }
#pragma unroll
    for (int m = 0; m < 4; ++m)
#pragma unroll
        for (int n = 0; n < 4; ++n)
#pragma unroll
            for (int r = 0; r < 4; ++r)
                atomicAdd(&Of[(size_t)(bb * 128 + wr + m * 16 + lg * 4 + r) * 1024 +
                              n0 + wc + n * 16 + l15],
                          acc[m][n][r]);
}

// ----------------------------- split-precision NT GEMM (pk / pv, tiny M) --
// C f32 = split(A f32) @ (Bh+Bl)^T + rowscale[row%128]*bias[col].  BK=32.
// blockIdx.z selects {EHf,Wk,bk,sE->pkf} vs {DHf,Wv,bv,sD->pvf}.
__global__ __launch_bounds__(256) void gemm_split2(
    const float* __restrict__ A0, const _Float16* __restrict__ Bh0,
    const _Float16* __restrict__ Bl0, const float* __restrict__ bias0,
    const float* __restrict__ rs0, float* __restrict__ C0,
    const float* __restrict__ A1, const _Float16* __restrict__ Bh1,
    const _Float16* __restrict__ Bl1, const float* __restrict__ bias1,
    const float* __restrict__ rs1, float* __restrict__ C1) {
    const int Kd = 1024, N = 1024;
    const float* A = blockIdx.z ? A1 : A0;
    const _Float16* Bh = blockIdx.z ? Bh1 : Bh0;
    const _Float16* Bl = blockIdx.z ? Bl1 : Bl0;
    const float* bias = blockIdx.z ? bias1 : bias0;
    const float* rowscale = blockIdx.z ? rs1 : rs0;
    float* C = blockIdx.z ? C1 : C0;
    __shared__ _Float16 Ah[128 * 40], Al[128 * 40], Bhs[128 * 40], Bls[128 * 40];
    const int tid = threadIdx.x, lane = tid & 63, wave = tid >> 6;
    const int l15 = lane & 15, lg = lane >> 4;
    const int row0 = blockIdx.x * 128, col0 = blockIdx.y * 128;
    const int wr = (wave >> 1) * 64, wc = (wave & 1) * 64;
    f32x4 acc[4][4];
#pragma unroll
    for (int m = 0; m < 4; ++m)
#pragma unroll
        for (int n = 0; n < 4; ++n) acc[m][n] = (f32x4)0.0f;

    for (int k0 = 0; k0 < Kd; k0 += 32) {
        __syncthreads();
#pragma unroll
        for (int i = 0; i < 2; ++i) {
            int u = tid + 256 * i;
            int r = u >> 2, c8 = (u & 3) * 8;
            const float* src = A + (size_t)(row0 + r) * Kd + k0 + c8;
            f32x4 v0 = *reinterpret_cast<const f32x4*>(src);
            f32x4 v1 = *reinterpret_cast<const f32x4*>(src + 4);
            f16x8 h8, l8;
#pragma unroll
            for (int j = 0; j < 4; ++j) {
                _Float16 hb = (_Float16)v0[j];
                h8[j] = hb; l8[j] = (_Float16)(v0[j] - (float)hb);
            }
#pragma unroll
            for (int j = 0; j < 4; ++j) {
                _Float16 hb = (_Float16)v1[j];
                h8[4 + j] = hb; l8[4 + j] = (_Float16)(v1[j] - (float)hb);
            }
            *reinterpret_cast<f16x8*>(&Ah[r * 40 + c8]) = h8;
            *reinterpret_cast<f16x8*>(&Al[r * 40 + c8]) = l8;
            *reinterpret_cast<f16x8*>(&Bhs[r * 40 + c8]) =
                *reinterpret_cast<const f16x8*>(Bh + (size_t)(col0 + r) * Kd + k0 + c8);
            *reinterpret_cast<f16x8*>(&Bls[r * 40 + c8]) =
                *reinterpret_cast<const f16x8*>(Bl + (size_t)(col0 + r) * Kd + k0 + c8);
        }
        __syncthreads();
        f16x8 ah[4], al[4], bh[4], bl[4];
#pragma unroll
        for (int m = 0; m < 4; ++m) {
            ah[m] = *reinterpret_cast<const f16x8*>(&Ah[(wr + m * 16 + l15) * 40 + lg * 8]);
            al[m] = *reinterpret_cast<const f16x8*>(&Al[(wr + m * 16 + l15) * 40 + lg * 8]);
        }
#pragma unroll
        for (int n = 0; n < 4; ++n) {
            bh[n] = *reinterpret_cast<const f16x8*>(&Bhs[(wc + n * 16 + l15) * 40 + lg * 8]);
            bl[n] = *reinterpret_cast<const f16x8*>(&Bls[(wc + n * 16 + l15) * 40 + lg * 8]);
        }
#pragma unroll
        for (int m = 0; m < 4; ++m)
#pragma unroll
            for (int n = 0; n < 4; ++n) {
                acc[m][n] = mfma16(ah[m], bh[n], acc[m][n]);
                acc[m][n] = mfma16(al[m], bh[n], acc[m][n]);
                acc[m][n] = mfma16(ah[m], bl[n], acc[m][n]);
            }
    }
#pragma unroll
    for (int m = 0; m < 4; ++m)
#pragma unroll
        for (int n = 0; n < 4; ++n) {
            int colg = col0 + wc + n * 16 + l15;
            float bi = bias[colg];
#pragma unroll
            for (int r = 0; r < 4; ++r) {
                int rowg = row0 + wr + m * 16 + lg * 4 + r;
                C[(size_t)rowg * N + colg] = acc[m][n][r] + rowscale[rowg & 127] * bi;
            }
        }
}

// --------------------------------------------- prep: pk->hi/lo, pv->pvT f16 --
// grid 64 = (b,h).  PKH/PKL keep the [512][1024] layout; PVT is [bh][64][128].
__global__ __launch_bounds__(256) void prep_attn(
    const float* __restrict__ pkf, const float* __restrict__ pvf,
    _Float16* __restrict__ PKH, _Float16* __restrict__ PKL,
    _Float16* __restrict__ PVT) {
    __shared__ _Float16 tr[64 * 136];
    const int bh = blockIdx.x, bb = bh >> 4, h = bh & 15;
    const int tid = threadIdx.x;
    const int rr = tid >> 4, c4 = (tid & 15) * 4;
#pragma unroll
    for (int p = 0; p < 8; ++p) {
        int k = p * 16 + rr;
        size_t idx = (size_t)(bb * 128 + k) * 1024 + h * 64 + c4;
        f32x4 v = *reinterpret_cast<const f32x4*>(pkf + idx);
        f16x4 hi, lo;
#pragma unroll
        for (int j = 0; j < 4; ++j) {
            _Float16 hb = (_Float16)v[j];
            hi[j] = hb; lo[j] = (_Float16)(v[j] - (float)hb);
        }
        *reinterpret_cast<f16x4*>(PKH + idx) = hi;
        *reinterpret_cast<f16x4*>(PKL + idx) = lo;
        // pv: transpose into LDS [d][k] (stride 136 f16 = 272B, 16B-aligned)
        f32x4 w = *reinterpret_cast<const f32x4*>(
            pvf + (size_t)(bb * 128 + k) * 1024 + h * 64 + c4);
#pragma unroll
        for (int j = 0; j < 4; ++j) tr[(c4 + j) * 136 + k] = (_Float16)w[j];
    }
    __syncthreads();
#pragma unroll
    for (int p = 0; p < 4; ++p) {
        int u = p * 256 + tid;
        int d = u >> 4, c = (u & 15) * 8;
        f16x8 w = *reinterpret_cast<const f16x8*>(&tr[d * 136 + c]);
        *reinterpret_cast<f16x8*>(PVT + (size_t)bh * 8192 + d * 128 + c) = w;
    }
}

// ------------------------------------------------------- fused attention --
// Per block: (st, h, b) -> 128 q-rows. LDS: pkh 16K + pkl 16K + pvt 16K;
// P (4 waves x 32 x 128 f16, 16B-XOR swizzle) aliases pkh+pkl. All tiles
// staged via global_load_lds with chunk-XOR swizzled sources.
__global__ __launch_bounds__(256) void attn_fused(
    const float* __restrict__ Qf, const _Float16* __restrict__ PKH,
    const _Float16* __restrict__ PKL, const _Float16* __restrict__ PVT,
    float* __restrict__ Out) {
    __shared__ _Float16 smem[24576];          // 48 KiB
    const int tid = threadIdx.x, lane = tid & 63, wave = tid >> 6;
    const int l15 = lane & 15, lg = lane >> 4;
    const int st = blockIdx.x, h = blockIdx.y, bb = blockIdx.z;

    // ---- async stage pkh/pkl ([128][64] f16, 8 chunks/row, swizzled) and
    //      pvt ([64][128] f16, 16 chunks/row, swizzled)
    {
        const _Float16* pkh_g = PKH + (size_t)(bb * 128) * 1024 + h * 64;
        const _Float16* pkl_g = PKL + (size_t)(bb * 128) * 1024 + h * 64;
        const _Float16* pvt_g = PVT + (size_t)(bb * 16 + h) * 8192;
        const int su = wave * 64 + lane;
#pragma unroll
        for (int it = 0; it < 4; ++it) {
            int u = it * 256 + su;
            int ub = it * 256 + wave * 64;
            {   // pk: r = u>>3 (k-row), c = u&7
                int r = u >> 3, c = u & 7;
                int sc = (c ^ (r & 7)) * 8;
                gload16(pkh_g + (size_t)r * 1024 + sc, &smem[ub * 8]);
                gload16(pkl_g + (size_t)r * 1024 + sc, &smem[8192 + ub * 8]);
            }
            {   // pvt: r = u>>4 (d-row), c = u&15
                int r = u >> 4, c = u & 15;
                int sc = (c ^ (r & 7)) * 8;
                gload16(pvt_g + r * 128 + sc, &smem[16384 + ub * 8]);
            }
        }
    }
    // ---- q fragments (hi/lo split from f32, overlaps the LDS DMA)
    const int srow0 = bb * 4096 + st * 128 + wave * 32;
    f16x8 qh[2][2], ql[2][2];
#pragma unroll
    for (int m = 0; m < 2; ++m)
#pragma unroll
        for (int kk = 0; kk < 2; ++kk) {
            const float* src =
                Qf + (size_t)(srow0 + m * 16 + l15) * 1024 + h * 64 + kk * 32 + lg * 8;
            f32x4 v0 = *reinterpret_cast<const f32x4*>(src);
            f32x4 v1 = *reinterpret_cast<const f32x4*>(src + 4);
            f16x8 hh, ll;
#pragma unroll
            for (int j = 0; j < 4; ++j) {
                _Float16 hb = (_Float16)v0[j];
                hh[j] = hb; ll[j] = (_Float16)(v0[j] - (float)hb);
            }
#pragma unroll
            for (int j = 0; j < 4; ++j) {
                _Float16 hb = (_Float16)v1[j];
                hh[4 + j] = hb; ll[4 + j] = (_Float16)(v1[j] - (float)hb);
            }
            qh[m][kk] = hh;
            ql[m][kk] = ll;
        }
    __syncthreads();   // drains vmcnt: all LDS tiles resident

    // ---- scores (3-term split), K=64
    f32x4 acc[2][8];
#pragma unroll
    for (int m = 0; m < 2; ++m)
#pragma unroll
        for (int n = 0; n < 8; ++n) acc[m][n] = (f32x4)0.0f;
#pragma unroll
    for (int kk = 0; kk < 2; ++kk)
#pragma unroll
        for (int n = 0; n < 8; ++n) {
            int ro = (n * 16 + l15) * 64 + (((kk * 4 + lg) ^ (l15 & 7)) * 8);
            f16x8 bh = *reinterpret_cast<const f16x8*>(&smem[ro]);
            f16x8 bl = *reinterpret_cast<const f16x8*>(&smem[8192 + ro]);
#pragma unroll
            for (int m = 0; m < 2; ++m) {
                acc[m][n] = mfma16(qh[m][kk], bh, acc[m][n]);
                acc[m][n] = mfma16(ql[m][kk], bh, acc[m][n]);
                acc[m][n] = mfma16(qh[m][kk], bl, acc[m][n]);
            }
        }

    // ---- softmax over 128 cols (8 frags x 16 lanes), deferred 1/denom
    float mx[2][4], inv[2][4];
#pragma unroll
    for (int m = 0; m < 2; ++m)
#pragma unroll
        for (int r = 0; r < 4; ++r) {
            float v = -1e30f;
#pragma unroll
            for (int n = 0; n < 8; ++n) v = fmaxf(v, acc[m][n][r]);
#pragma unroll
            for (int msk = 1; msk < 16; msk <<= 1) v = fmaxf(v, __shfl_xor(v, msk));
            mx[m][r] = v * 0.125f;
        }
#pragma unroll
    for (int m = 0; m < 2; ++m)
#pragma unroll
        for (int n = 0; n < 8; ++n)
#pragma unroll
            for (int r = 0; r < 4; ++r)
                acc[m][n][r] = __expf(acc[m][n][r] * 0.125f - mx[m][r]);
#pragma unroll
    for (int m = 0; m < 2; ++m)
#pragma unroll
        for (int r = 0; r < 4; ++r) {
            float s = 0.f;
#pragma unroll
            for (int n = 0; n < 8; ++n) s += acc[m][n][r];
#pragma unroll
            for (int msk = 1; msk < 16; msk <<= 1) s += __shfl_xor(s, msk);
            inv[m][r] = 1.0f / s;
        }
    __syncthreads();   // all waves done reading pk: safe to alias P

    // ---- P -> LDS (aliases pkh+pkl), 16B-granule XOR swizzle per row
    _Float16* pw = smem + wave * 4096;
#pragma unroll
    for (int m = 0; m < 2; ++m)
#pragma unroll
        for (int n = 0; n < 8; ++n)
#pragma unroll
            for (int r = 0; r < 4; ++r) {
                int row = m * 16 + lg * 4 + r;
                int col = n * 16 + l15;
                pw[row * 128 + (col ^ ((row & 7) << 3))] = (_Float16)acc[m][n][r];
            }
    // own-wave write->read: lgkmcnt dependency only, no barrier needed

    // ---- PV: ctx[32 x 64] per wave, K=128 (4 ksteps)
    f32x4 o[2][4];
#pragma unroll
    for (int m = 0; m < 2; ++m)
#pragma unroll
        for (int n = 0; n < 4; ++n) o[m][n] = (f32x4)0.0f;
#pragma unroll
    for (int ks = 0; ks < 4; ++ks) {
        f16x8 af[2];
#pragma unroll
        for (int m = 0; m < 2; ++m) {
            int row = m * 16 + l15;
            af[m] = *reinterpret_cast<const f16x8*>(
                &pw[row * 128 + (((ks * 4 + lg) ^ (row & 7)) * 8)]);
        }
#pragma unroll
        for (int n = 0; n < 4; ++n) {
            int dd = n * 16 + l15;
            f16x8 bfr = *reinterpret_cast<const f16x8*>(
                &smem[16384 + dd * 128 + (((ks * 4 + lg) ^ (dd & 7)) * 8)]);
#pragma unroll
            for (int m = 0; m < 2; ++m) o[m][n] = mfma16(af[m], bfr, o[m][n]);
        }
    }
#pragma unroll
    for (int m = 0; m < 2; ++m)
#pragma unroll
        for (int n = 0; n < 4; ++n)
#pragma unroll
            for (int r = 0; r < 4; ++r) {
                int row = srow0 + m * 16 + lg * 4 + r;
                Out[(size_t)row * 1024 + h * 64 + n * 16 + l15] = o[m][n][r] * inv[m][r];
            }
}

// ---------------------------------------------------------------------------
extern "C" void kernel_launch(void* const* d_in, const int* in_sizes, int n_in,
                              void* d_out, int out_size, void* d_ws, size_t ws_size,
                              hipStream_t stream) {
    const float* hs = (const float*)d_in[0];
    const float* Wq = (const float*)d_in[1];
    const float* bq = (const float*)d_in[2];
    const float* Wk = (const float*)d_in[3];
    const float* bk = (const float*)d_in[4];
    const float* Wv = (const float*)d_in[5];
    const float* bv = (const float*)d_in[6];
    const float* Em = (const float*)d_in[7];
    const float* Dm = (const float*)d_in[8];
    float* out = (float*)d_out;
    char* ws = (char*)d_ws;

    // workspace layout (bytes)
    _Float16* hsB = (_Float16*)(ws + 0);                  // 33,554,432
    _Float16* WqB = (_Float16*)(ws + 33554432);           //  2,097,152
    _Float16* WkH = (_Float16*)(ws + 35651584);
    _Float16* WkL = (_Float16*)(ws + 37748736);
    _Float16* WvH = (_Float16*)(ws + 39845888);
    _Float16* WvL = (_Float16*)(ws + 41943040);
    _Float16* EB  = (_Float16*)(ws + 44040192);           //  1,048,576
    _Float16* DB  = (_Float16*)(ws + 45088768);
    float* sE  = (float*)(ws + 46137344);                 //        512
    float* sD  = (float*)(ws + 46137856);
    float* Qf  = (float*)(ws + 46138368);                 // 67,108,864
    float* EHf = (float*)(ws + 113247232);                //  2,097,152
    float* DHf = (float*)(ws + 115344384);
    float* pkf = (float*)(ws + 117441536);
    float* pvf = (float*)(ws + 119538688);
    _Float16* PKH = (_Float16*)(ws + 121635840);          //  1,048,576
    _Float16* PKL = (_Float16*)(ws + 122684416);
    _Float16* PVT = (_Float16*)(ws + 123732992);          // end 124,781,568

    // 1. dtype converts
    cvt_f16<<<2048, 256, 0, stream>>>(hs, hsB, 16777216 / 4);
    cvt_f16<<<1024, 256, 0, stream>>>(Wq, WqB, 1048576 / 4);
    cvt_hilo2<<<dim3(1024, 2), 256, 0, stream>>>(Wk, WkH, WkL, Wv, WvH, WvL,
                                                 1048576 / 4);
    cvt_f16_2<<<dim3(512, 2), 256, 0, stream>>>(Em, EB, Dm, DB, 524288 / 4);
    // 2. bias-correction row sums
    rowsum_k<<<256, 256, 0, stream>>>(Em, Dm, sE, sD);
    // 3. Q projection
    gemm_nt_bias_f32<<<dim3(128, 8), 256, 0, stream>>>(hsB, WqB, bq, Qf,
                                                       16384, 1024, 1024);
    // 4. EH = E @ hs, DH = D @ hs (split-K atomics, merged launch)
    hipMemsetAsync(EHf, 0, 2 * 512 * 1024 * sizeof(float), stream);
    eproj2<<<dim3(8, 8, 8), 256, 0, stream>>>(EB, DB, hsB, EHf, DHf);
    // 5. pk = EH @ Wk^T + sE*bk ; pv = DH @ Wv^T + sD*bv (merged launch)
    gemm_split2<<<dim3(4, 8, 2), 256, 0, stream>>>(EHf, WkH, WkL, bk, sE, pkf,
                                                   DHf, WvH, WvL, bv, sD, pvf);
    // 6. prep f16 pk hi/lo + pvT
    prep_attn<<<64, 256, 0, stream>>>(pkf, pvf, PKH, PKL, PVT);
    // 7. fused attention
    attn_fused<<<dim3(32, 16, 4), 256, 0, stream>>>(Qf, PKH, PKL, PVT, out);
}

// Round 4
// 176.630 us; speedup vs baseline: 1.5675x; 1.1684x over previous
//
#include <hip/hip_runtime.h>
#include <hip/hip_bf16.h>
#include <stdint.h>

// ---------------------------------------------------------------------------
// Linformer attention, MI355X (gfx950).
// B=4, S=4096, DM=1024, H=16, DH=64, K=128.
//
// Pipeline (pk = (E*hs)*Wk^T + (sum_s E)*bk^T  -- avoids computing K,V):
//   1. convert hs, Wq, E, D -> fp16; Wk, Wv -> fp16 hi/lo pairs
//   2. rowsum(E), rowsum(D) -> sE, sD  (bias-correction terms)
//   3. QH = f16(hs_f16 @ Wq_f16^T + bq)  -- dbuf-prefetch GEMM, counted vmcnt
//   4. EHf = E_f16 @ hs_f16  (split-K atomics, E and D in one launch)
//   5. pkf/pvf = split(EHf/DHf) @ (Wh,Wl)^T + s*b  (64x64 tiles, 256 blocks)
//   6. prep_attn: pkf -> PKH/PKL f16; pvf -> PVT f16 [bh][d][k]
//   7. attn: gload_lds-staged pk hi/lo + pvT (XOR-swizzled), 2-term scores
//      (qh*pkh + qh*pkl), wave-local softmax, P aliased over pk LDS, PV.
// ---------------------------------------------------------------------------

typedef __attribute__((ext_vector_type(8))) _Float16 f16x8;   // 4 VGPR
typedef __attribute__((ext_vector_type(4))) _Float16 f16x4;
typedef __attribute__((ext_vector_type(4))) float    f32x4;

__device__ __forceinline__ f32x4 mfma16(f16x8 a, f16x8 b, f32x4 c) {
    return __builtin_amdgcn_mfma_f32_16x16x32_f16(a, b, c, 0, 0, 0);
}

// async global->LDS, 16B per lane; LDS dest = wave-uniform base + lane*16
__device__ __forceinline__ void gload16(const void* g, void* l) {
    __builtin_amdgcn_global_load_lds(
        (const __attribute__((address_space(1))) void*)g,
        (__attribute__((address_space(3))) void*)l, 16, 0, 0);
}

// ---------------------------------------------------------------- converts --
__global__ __launch_bounds__(256) void cvt_f16(const float* __restrict__ in,
                                               _Float16* __restrict__ out, int n4) {
    int i = blockIdx.x * 256 + threadIdx.x;
    int stride = gridDim.x * 256;
    for (; i < n4; i += stride) {
        f32x4 v = reinterpret_cast<const f32x4*>(in)[i];
        f16x4 o;
#pragma unroll
        for (int j = 0; j < 4; ++j) o[j] = (_Float16)v[j];
        reinterpret_cast<f16x4*>(out)[i] = o;
    }
}

__global__ __launch_bounds__(256) void cvt_f16_2(const float* __restrict__ in0,
                                                 _Float16* __restrict__ out0,
                                                 const float* __restrict__ in1,
                                                 _Float16* __restrict__ out1, int n4) {
    const float* in = blockIdx.y ? in1 : in0;
    _Float16* out = blockIdx.y ? out1 : out0;
    int i = blockIdx.x * 256 + threadIdx.x;
    int stride = gridDim.x * 256;
    for (; i < n4; i += stride) {
        f32x4 v = reinterpret_cast<const f32x4*>(in)[i];
        f16x4 o;
#pragma unroll
        for (int j = 0; j < 4; ++j) o[j] = (_Float16)v[j];
        reinterpret_cast<f16x4*>(out)[i] = o;
    }
}

__global__ __launch_bounds__(256) void cvt_hilo2(const float* __restrict__ in0,
                                                 _Float16* __restrict__ hi0,
                                                 _Float16* __restrict__ lo0,
                                                 const float* __restrict__ in1,
                                                 _Float16* __restrict__ hi1,
                                                 _Float16* __restrict__ lo1, int n4) {
    const float* in = blockIdx.y ? in1 : in0;
    _Float16* hi = blockIdx.y ? hi1 : hi0;
    _Float16* lo = blockIdx.y ? lo1 : lo0;
    int i = blockIdx.x * 256 + threadIdx.x;
    int stride = gridDim.x * 256;
    for (; i < n4; i += stride) {
        f32x4 v = reinterpret_cast<const f32x4*>(in)[i];
        f16x4 h, l;
#pragma unroll
        for (int j = 0; j < 4; ++j) {
            _Float16 hb = (_Float16)v[j];
            h[j] = hb;
            l[j] = (_Float16)(v[j] - (float)hb);
        }
        reinterpret_cast<f16x4*>(hi)[i] = h;
        reinterpret_cast<f16x4*>(lo)[i] = l;
    }
}

// rowsum over S=4096 for E and D: blocks 0..127 -> E rows, 128..255 -> D rows
__global__ __launch_bounds__(256) void rowsum_k(const float* __restrict__ E,
                                                const float* __restrict__ D,
                                                float* __restrict__ sE,
                                                float* __restrict__ sD) {
    __shared__ float red[256];
    const int blk = blockIdx.x;
    const float* src = (blk < 128) ? E : D;
    float* dst = (blk < 128) ? sE : sD;
    const int row = blk & 127;
    float s = 0.f;
    for (int i = threadIdx.x; i < 4096; i += 256) s += src[(size_t)row * 4096 + i];
    red[threadIdx.x] = s;
    __syncthreads();
    for (int off = 128; off > 0; off >>= 1) {
        if ((int)threadIdx.x < off) red[threadIdx.x] += red[threadIdx.x + off];
        __syncthreads();
    }
    if (threadIdx.x == 0) dst[row] = red[0];
}

// --------------------------------------------------- Q projection (f16 out) --
// QH[M,N] f16 = f16(A[M,K]f16 * B[N,K]f16^T + bias[N]).  128x128 tile, BK=64,
// double-buffered LDS, prefetch with counted vmcnt (never 0 mid-loop).
__global__ __launch_bounds__(256) void gemm_q_f16(
    const _Float16* __restrict__ A, const _Float16* __restrict__ B,
    const float* __restrict__ bias, _Float16* __restrict__ Q) {
    const int Kd = 1024, N = 1024, NT = 16;     // K-steps of 64
    __shared__ _Float16 Asm[2][128 * 64];
    __shared__ _Float16 Bsm[2][128 * 64];
    const int tid = threadIdx.x, lane = tid & 63, wave = tid >> 6;
    const int l15 = lane & 15, lg = lane >> 4;
    const int row0 = blockIdx.x * 128, col0 = blockIdx.y * 128;
    const int wr = (wave >> 1) * 64, wc = (wave & 1) * 64;
    f32x4 acc[4][4];
#pragma unroll
    for (int m = 0; m < 4; ++m)
#pragma unroll
        for (int n = 0; n < 4; ++n) acc[m][n] = (f32x4)0.0f;

    // hoisted per-lane source pointers (swizzled chunk) + LDS slot bases
    const _Float16* aSrc[4];
    const _Float16* bSrc[4];
    int ub[4];
#pragma unroll
    for (int it = 0; it < 4; ++it) {
        int u = it * 256 + tid;
        int r = u >> 3, c = u & 7;
        int sc = (c ^ (r & 7)) * 8;
        aSrc[it] = A + (size_t)(row0 + r) * Kd + sc;
        bSrc[it] = B + (size_t)(col0 + r) * Kd + sc;
        ub[it] = it * 256 + wave * 64;
    }
    auto stage = [&](int buf, int t) {
        const int k0 = t * 64;
#pragma unroll
        for (int it = 0; it < 4; ++it) {
            gload16(aSrc[it] + k0, &Asm[buf][ub[it] * 8]);
            gload16(bSrc[it] + k0, &Bsm[buf][ub[it] * 8]);
        }
    };

    stage(0, 0);
#pragma unroll 1
    for (int t = 0; t < NT; ++t) {
        const int cur = t & 1;
        if (t < NT - 1) {
            stage(cur ^ 1, t + 1);                       // prefetch stays in flight
            asm volatile("s_waitcnt vmcnt(8)" ::: "memory");
        } else {
            asm volatile("s_waitcnt vmcnt(0)" ::: "memory");
        }
        __builtin_amdgcn_s_barrier();                    // buf[cur] ready
#pragma unroll
        for (int kk = 0; kk < 2; ++kk) {
            f16x8 af[4], bfr[4];
#pragma unroll
            for (int m = 0; m < 4; ++m)
                af[m] = *reinterpret_cast<const f16x8*>(
                    &Asm[cur][(wr + m * 16 + l15) * 64 + (((kk * 4 + lg) ^ (l15 & 7)) * 8)]);
#pragma unroll
            for (int n = 0; n < 4; ++n)
                bfr[n] = *reinterpret_cast<const f16x8*>(
                    &Bsm[cur][(wc + n * 16 + l15) * 64 + (((kk * 4 + lg) ^ (l15 & 7)) * 8)]);
#pragma unroll
            for (int m = 0; m < 4; ++m)
#pragma unroll
                for (int n = 0; n < 4; ++n) acc[m][n] = mfma16(af[m], bfr[n], acc[m][n]);
        }
        __builtin_amdgcn_s_barrier();                    // all done reading buf[cur]
    }
#pragma unroll
    for (int m = 0; m < 4; ++m)
#pragma unroll
        for (int n = 0; n < 4; ++n) {
            int colg = col0 + wc + n * 16 + l15;
            float bi = bias[colg];
#pragma unroll
            for (int r = 0; r < 4; ++r) {
                int rowg = row0 + wr + m * 16 + lg * 4 + r;
                Q[(size_t)rowg * N + colg] = (_Float16)(acc[m][n][r] + bi);
            }
        }
}

// -------------------------------------------- E/D @ hs projection (NN GEMM) --
// Of[b*128+kk, n] += sum_s Emat[kk,s]*X[b*4096+s, n]; split-K over blockIdx.x.
// blockIdx.z: 0..3 -> E batches, 4..7 -> D batches.
__global__ __launch_bounds__(256) void eproj2(const _Float16* __restrict__ EB,
                                              const _Float16* __restrict__ DB,
                                              const _Float16* __restrict__ X,
                                              float* __restrict__ EHf,
                                              float* __restrict__ DHf) {
    __shared__ _Float16 Ea[128 * 72];
    __shared__ _Float16 BT[128 * 72];
    const int tid = threadIdx.x, lane = tid & 63, wave = tid >> 6;
    const int l15 = lane & 15, lg = lane >> 4;
    const int sc = blockIdx.x;          // K-chunk 0..7 (512 rows each)
    const int n0 = blockIdx.y * 128;
    const int bb = blockIdx.z & 3;
    const _Float16* Emat = (blockIdx.z >> 2) ? DB : EB;
    float* Of = (blockIdx.z >> 2) ? DHf : EHf;
    const int wr = (wave >> 1) * 64, wc = (wave & 1) * 64;
    const int nb = tid & 31, sb = tid >> 5;
    f32x4 acc[4][4];
#pragma unroll
    for (int m = 0; m < 4; ++m)
#pragma unroll
        for (int n = 0; n < 4; ++n) acc[m][n] = (f32x4)0.0f;

    for (int ks = 0; ks < 512; ks += 64) {
        const int s0 = sc * 512 + ks;
        __syncthreads();
#pragma unroll
        for (int i = 0; i < 4; ++i) {  // A tile: E [128 kk][64 s]
            int u = tid + 256 * i;
            int r = u >> 3, c8 = (u & 7) * 8;
            *reinterpret_cast<f16x8*>(&Ea[r * 72 + c8]) =
                *reinterpret_cast<const f16x8*>(Emat + (size_t)r * 4096 + s0 + c8);
        }
        {   // B tile: X [64 s][128 n] -> transposed BT[n][s]
            f16x4 rr[8];
#pragma unroll
            for (int i = 0; i < 8; ++i)
                rr[i] = *reinterpret_cast<const f16x4*>(
                    X + (size_t)(bb * 4096 + s0 + sb * 8 + i) * 1024 + n0 + nb * 4);
#pragma unroll
            for (int j = 0; j < 4; ++j) {
                f16x8 w;
#pragma unroll
                for (int i = 0; i < 8; ++i) w[i] = rr[i][j];
                *reinterpret_cast<f16x8*>(&BT[(nb * 4 + j) * 72 + sb * 8]) = w;
            }
        }
        __syncthreads();
#pragma unroll
        for (int kk = 0; kk < 2; ++kk) {
            f16x8 af[4], bfr[4];
#pragma unroll
            for (int m = 0; m < 4; ++m)
                af[m] = *reinterpret_cast<const f16x8*>(
                    &Ea[(wr + m * 16 + l15) * 72 + kk * 32 + lg * 8]);
#pragma unroll
            for (int n = 0; n < 4; ++n)
                bfr[n] = *reinterpret_cast<const f16x8*>(
                    &BT[(wc + n * 16 + l15) * 72 + kk * 32 + lg * 8]);
#pragma unroll
            for (int m = 0; m < 4; ++m)
#pragma unroll
                for (int n = 0; n < 4; ++n) acc[m][n] = mfma16(af[m], bfr[n], acc[m][n]);
        }
    }
#pragma unroll
    for (int m = 0; m < 4; ++m)
#pragma unroll
        for (int n = 0; n < 4; ++n)
#pragma unroll
            for (int r = 0; r < 4; ++r)
                atomicAdd(&Of[(size_t)(bb * 128 + wr + m * 16 + lg * 4 + r) * 1024 +
                              n0 + wc + n * 16 + l15],
                          acc[m][n][r]);
}

// ----------------------------- split-precision NT GEMM (pk / pv, tiny M) --
// C f32 = split(A f32) @ (Bh+Bl)^T + rowscale[row%128]*bias[col].  BK=32,
// 64x64 tile -> grid (8,16,2) = 256 blocks (full CU coverage).
__global__ __launch_bounds__(256) void gemm_split2(
    const float* __restrict__ A0, const _Float16* __restrict__ Bh0,
    const _Float16* __restrict__ Bl0, const float* __restrict__ bias0,
    const float* __restrict__ rs0, float* __restrict__ C0,
    const float* __restrict__ A1, const _Float16* __restrict__ Bh1,
    const _Float16* __restrict__ Bl1, const float* __restrict__ bias1,
    const float* __restrict__ rs1, float* __restrict__ C1) {
    const int Kd = 1024, N = 1024;
    const float* A = blockIdx.z ? A1 : A0;
    const _Float16* Bh = blockIdx.z ? Bh1 : Bh0;
    const _Float16* Bl = blockIdx.z ? Bl1 : Bl0;
    const float* bias = blockIdx.z ? bias1 : bias0;
    const float* rowscale = blockIdx.z ? rs1 : rs0;
    float* C = blockIdx.z ? C1 : C0;
    __shared__ _Float16 Ah[64 * 40], Al[64 * 40], Bhs[64 * 40], Bls[64 * 40];
    const int tid = threadIdx.x, lane = tid & 63, wave = tid >> 6;
    const int l15 = lane & 15, lg = lane >> 4;
    const int row0 = blockIdx.x * 64, col0 = blockIdx.y * 64;
    const int wr = (wave >> 1) * 32, wc = (wave & 1) * 32;
    f32x4 acc[2][2];
#pragma unroll
    for (int m = 0; m < 2; ++m)
#pragma unroll
        for (int n = 0; n < 2; ++n) acc[m][n] = (f32x4)0.0f;

    const int r = tid >> 2, c8 = (tid & 3) * 8;
    for (int k0 = 0; k0 < Kd; k0 += 32) {
        __syncthreads();
        {   // A: 64 rows x 32 k f32 -> hi/lo f16
            const float* src = A + (size_t)(row0 + r) * Kd + k0 + c8;
            f32x4 v0 = *reinterpret_cast<const f32x4*>(src);
            f32x4 v1 = *reinterpret_cast<const f32x4*>(src + 4);
            f16x8 h8, l8;
#pragma unroll
            for (int j = 0; j < 4; ++j) {
                _Float16 hb = (_Float16)v0[j];
                h8[j] = hb; l8[j] = (_Float16)(v0[j] - (float)hb);
            }
#pragma unroll
            for (int j = 0; j < 4; ++j) {
                _Float16 hb = (_Float16)v1[j];
                h8[4 + j] = hb; l8[4 + j] = (_Float16)(v1[j] - (float)hb);
            }
            *reinterpret_cast<f16x8*>(&Ah[r * 40 + c8]) = h8;
            *reinterpret_cast<f16x8*>(&Al[r * 40 + c8]) = l8;
            // B: 64 rows x 32 k, precomputed hi/lo
            *reinterpret_cast<f16x8*>(&Bhs[r * 40 + c8]) =
                *reinterpret_cast<const f16x8*>(Bh + (size_t)(col0 + r) * Kd + k0 + c8);
            *reinterpret_cast<f16x8*>(&Bls[r * 40 + c8]) =
                *reinterpret_cast<const f16x8*>(Bl + (size_t)(col0 + r) * Kd + k0 + c8);
        }
        __syncthreads();
        f16x8 ah[2], al[2], bh[2], bl[2];
#pragma unroll
        for (int m = 0; m < 2; ++m) {
            ah[m] = *reinterpret_cast<const f16x8*>(&Ah[(wr + m * 16 + l15) * 40 + lg * 8]);
            al[m] = *reinterpret_cast<const f16x8*>(&Al[(wr + m * 16 + l15) * 40 + lg * 8]);
        }
#pragma unroll
        for (int n = 0; n < 2; ++n) {
            bh[n] = *reinterpret_cast<const f16x8*>(&Bhs[(wc + n * 16 + l15) * 40 + lg * 8]);
            bl[n] = *reinterpret_cast<const f16x8*>(&Bls[(wc + n * 16 + l15) * 40 + lg * 8]);
        }
#pragma unroll
        for (int m = 0; m < 2; ++m)
#pragma unroll
            for (int n = 0; n < 2; ++n) {
                acc[m][n] = mfma16(ah[m], bh[n], acc[m][n]);
                acc[m][n] = mfma16(al[m], bh[n], acc[m][n]);
                acc[m][n] = mfma16(ah[m], bl[n], acc[m][n]);
            }
    }
#pragma unroll
    for (int m = 0; m < 2; ++m)
#pragma unroll
        for (int n = 0; n < 2; ++n) {
            int colg = col0 + wc + n * 16 + l15;
            float bi = bias[colg];
#pragma unroll
            for (int rr2 = 0; rr2 < 4; ++rr2) {
                int rowg = row0 + wr + m * 16 + lg * 4 + rr2;
                C[(size_t)rowg * N + colg] = acc[m][n][rr2] + rowscale[rowg & 127] * bi;
            }
        }
}

// --------------------------------------------- prep: pk->hi/lo, pv->pvT f16 --
// grid 64 = (b,h).  PKH/PKL keep the [512][1024] layout; PVT is [bh][64][128].
__global__ __launch_bounds__(256) void prep_attn(
    const float* __restrict__ pkf, const float* __restrict__ pvf,
    _Float16* __restrict__ PKH, _Float16* __restrict__ PKL,
    _Float16* __restrict__ PVT) {
    __shared__ _Float16 tr[64 * 136];
    const int bh = blockIdx.x, bb = bh >> 4, h = bh & 15;
    const int tid = threadIdx.x;
    const int rr = tid >> 4, c4 = (tid & 15) * 4;
#pragma unroll
    for (int p = 0; p < 8; ++p) {
        int k = p * 16 + rr;
        size_t idx = (size_t)(bb * 128 + k) * 1024 + h * 64 + c4;
        f32x4 v = *reinterpret_cast<const f32x4*>(pkf + idx);
        f16x4 hi, lo;
#pragma unroll
        for (int j = 0; j < 4; ++j) {
            _Float16 hb = (_Float16)v[j];
            hi[j] = hb; lo[j] = (_Float16)(v[j] - (float)hb);
        }
        *reinterpret_cast<f16x4*>(PKH + idx) = hi;
        *reinterpret_cast<f16x4*>(PKL + idx) = lo;
        f32x4 w = *reinterpret_cast<const f32x4*>(
            pvf + (size_t)(bb * 128 + k) * 1024 + h * 64 + c4);
#pragma unroll
        for (int j = 0; j < 4; ++j) tr[(c4 + j) * 136 + k] = (_Float16)w[j];
    }
    __syncthreads();
#pragma unroll
    for (int p = 0; p < 4; ++p) {
        int u = p * 256 + tid;
        int d = u >> 4, c = (u & 15) * 8;
        f16x8 w = *reinterpret_cast<const f16x8*>(&tr[d * 136 + c]);
        *reinterpret_cast<f16x8*>(PVT + (size_t)bh * 8192 + d * 128 + c) = w;
    }
}

// ------------------------------------------------------- fused attention --
// Per block: (st, h, b) -> 128 q-rows. LDS: pkh 16K + pkl 16K + pvt 16K;
// P (4 waves x 32 x 128 f16) aliases pkh+pkl. 2-term scores (qh only).
__global__ __launch_bounds__(256) void attn_fused(
    const _Float16* __restrict__ QH, const _Float16* __restrict__ PKH,
    const _Float16* __restrict__ PKL, const _Float16* __restrict__ PVT,
    float* __restrict__ Out) {
    __shared__ _Float16 smem[24576];          // 48 KiB
    const int tid = threadIdx.x, lane = tid & 63, wave = tid >> 6;
    const int l15 = lane & 15, lg = lane >> 4;
    const int st = blockIdx.x, h = blockIdx.y, bb = blockIdx.z;

    // ---- async stage pkh/pkl ([128][64] f16) and pvt ([64][128] f16), swizzled
    {
        const _Float16* pkh_g = PKH + (size_t)(bb * 128) * 1024 + h * 64;
        const _Float16* pkl_g = PKL + (size_t)(bb * 128) * 1024 + h * 64;
        const _Float16* pvt_g = PVT + (size_t)(bb * 16 + h) * 8192;
        const int su = wave * 64 + lane;
#pragma unroll
        for (int it = 0; it < 4; ++it) {
            int u = it * 256 + su;
            int ub = it * 256 + wave * 64;
            {
                int r = u >> 3, c = u & 7;
                int sc = (c ^ (r & 7)) * 8;
                gload16(pkh_g + (size_t)r * 1024 + sc, &smem[ub * 8]);
                gload16(pkl_g + (size_t)r * 1024 + sc, &smem[8192 + ub * 8]);
            }
            {
                int r = u >> 4, c = u & 15;
                int sc = (c ^ (r & 7)) * 8;
                gload16(pvt_g + r * 128 + sc, &smem[16384 + ub * 8]);
            }
        }
    }
    // ---- q fragments: direct f16 loads (overlap the LDS DMA)
    const int srow0 = bb * 4096 + st * 128 + wave * 32;
    f16x8 qh[2][2];
#pragma unroll
    for (int m = 0; m < 2; ++m)
#pragma unroll
        for (int kk = 0; kk < 2; ++kk)
            qh[m][kk] = *reinterpret_cast<const f16x8*>(
                QH + (size_t)(srow0 + m * 16 + l15) * 1024 + h * 64 + kk * 32 + lg * 8);
    __syncthreads();   // drains vmcnt: all LDS tiles resident

    // ---- scores (2-term: qh*pkh + qh*pkl), K=64
    f32x4 acc[2][8];
#pragma unroll
    for (int m = 0; m < 2; ++m)
#pragma unroll
        for (int n = 0; n < 8; ++n) acc[m][n] = (f32x4)0.0f;
#pragma unroll
    for (int kk = 0; kk < 2; ++kk)
#pragma unroll
        for (int n = 0; n < 8; ++n) {
            int ro = (n * 16 + l15) * 64 + (((kk * 4 + lg) ^ (l15 & 7)) * 8);
            f16x8 bh = *reinterpret_cast<const f16x8*>(&smem[ro]);
            f16x8 bl = *reinterpret_cast<const f16x8*>(&smem[8192 + ro]);
#pragma unroll
            for (int m = 0; m < 2; ++m) {
                acc[m][n] = mfma16(qh[m][kk], bh, acc[m][n]);
                acc[m][n] = mfma16(qh[m][kk], bl, acc[m][n]);
            }
        }

    // ---- softmax over 128 cols (8 frags x 16 lanes), deferred 1/denom
    float mx[2][4], inv[2][4];
#pragma unroll
    for (int m = 0; m < 2; ++m)
#pragma unroll
        for (int r = 0; r < 4; ++r) {
            float v = -1e30f;
#pragma unroll
            for (int n = 0; n < 8; ++n) v = fmaxf(v, acc[m][n][r]);
#pragma unroll
            for (int msk = 1; msk < 16; msk <<= 1) v = fmaxf(v, __shfl_xor(v, msk));
            mx[m][r] = v * 0.125f;
        }
#pragma unroll
    for (int m = 0; m < 2; ++m)
#pragma unroll
        for (int n = 0; n < 8; ++n)
#pragma unroll
            for (int r = 0; r < 4; ++r)
                acc[m][n][r] = __expf(acc[m][n][r] * 0.125f - mx[m][r]);
#pragma unroll
    for (int m = 0; m < 2; ++m)
#pragma unroll
        for (int r = 0; r < 4; ++r) {
            float s = 0.f;
#pragma unroll
            for (int n = 0; n < 8; ++n) s += acc[m][n][r];
#pragma unroll
            for (int msk = 1; msk < 16; msk <<= 1) s += __shfl_xor(s, msk);
            inv[m][r] = 1.0f / s;
        }
    __syncthreads();   // all waves done reading pk: safe to alias P

    // ---- P -> LDS (aliases pkh+pkl), 16B-granule XOR swizzle per row
    _Float16* pw = smem + wave * 4096;
#pragma unroll
    for (int m = 0; m < 2; ++m)
#pragma unroll
        for (int n = 0; n < 8; ++n)
#pragma unroll
            for (int r = 0; r < 4; ++r) {
                int row = m * 16 + lg * 4 + r;
                int col = n * 16 + l15;
                pw[row * 128 + (col ^ ((row & 7) << 3))] = (_Float16)acc[m][n][r];
            }
    // own-wave write->read: lgkmcnt dependency only, no barrier needed

    // ---- PV: ctx[32 x 64] per wave, K=128 (4 ksteps)
    f32x4 o[2][4];
#pragma unroll
    for (int m = 0; m < 2; ++m)
#pragma unroll
        for (int n = 0; n < 4; ++n) o[m][n] = (f32x4)0.0f;
#pragma unroll
    for (int ks = 0; ks < 4; ++ks) {
        f16x8 af[2];
#pragma unroll
        for (int m = 0; m < 2; ++m) {
            int row = m * 16 + l15;
            af[m] = *reinterpret_cast<const f16x8*>(
                &pw[row * 128 + (((ks * 4 + lg) ^ (row & 7)) * 8)]);
        }
#pragma unroll
        for (int n = 0; n < 4; ++n) {
            int dd = n * 16 + l15;
            f16x8 bfr = *reinterpret_cast<const f16x8*>(
                &smem[16384 + dd * 128 + (((ks * 4 + lg) ^ (dd & 7)) * 8)]);
#pragma unroll
            for (int m = 0; m < 2; ++m) o[m][n] = mfma16(af[m], bfr, o[m][n]);
        }
    }
#pragma unroll
    for (int m = 0; m < 2; ++m)
#pragma unroll
        for (int n = 0; n < 4; ++n)
#pragma unroll
            for (int r = 0; r < 4; ++r) {
                int row = srow0 + m * 16 + lg * 4 + r;
                Out[(size_t)row * 1024 + h * 64 + n * 16 + l15] = o[m][n][r] * inv[m][r];
            }
}

// ---------------------------------------------------------------------------
extern "C" void kernel_launch(void* const* d_in, const int* in_sizes, int n_in,
                              void* d_out, int out_size, void* d_ws, size_t ws_size,
                              hipStream_t stream) {
    const float* hs = (const float*)d_in[0];
    const float* Wq = (const float*)d_in[1];
    const float* bq = (const float*)d_in[2];
    const float* Wk = (const float*)d_in[3];
    const float* bk = (const float*)d_in[4];
    const float* Wv = (const float*)d_in[5];
    const float* bv = (const float*)d_in[6];
    const float* Em = (const float*)d_in[7];
    const float* Dm = (const float*)d_in[8];
    float* out = (float*)d_out;
    char* ws = (char*)d_ws;

    // workspace layout (bytes)
    _Float16* hsB = (_Float16*)(ws + 0);                  // 33,554,432
    _Float16* WqB = (_Float16*)(ws + 33554432);           //  2,097,152
    _Float16* WkH = (_Float16*)(ws + 35651584);
    _Float16* WkL = (_Float16*)(ws + 37748736);
    _Float16* WvH = (_Float16*)(ws + 39845888);
    _Float16* WvL = (_Float16*)(ws + 41943040);
    _Float16* EB  = (_Float16*)(ws + 44040192);           //  1,048,576
    _Float16* DB  = (_Float16*)(ws + 45088768);
    float* sE  = (float*)(ws + 46137344);                 //        512
    float* sD  = (float*)(ws + 46137856);
    _Float16* QHq = (_Float16*)(ws + 46138368);           // 33,554,432 (f16 Q)
    float* EHf = (float*)(ws + 113247232);                //  2,097,152
    float* DHf = (float*)(ws + 115344384);
    float* pkf = (float*)(ws + 117441536);
    float* pvf = (float*)(ws + 119538688);
    _Float16* PKH = (_Float16*)(ws + 121635840);          //  1,048,576
    _Float16* PKL = (_Float16*)(ws + 122684416);
    _Float16* PVT = (_Float16*)(ws + 123732992);          // end 124,781,568

    // 1. dtype converts
    cvt_f16<<<2048, 256, 0, stream>>>(hs, hsB, 16777216 / 4);
    cvt_f16<<<1024, 256, 0, stream>>>(Wq, WqB, 1048576 / 4);
    cvt_hilo2<<<dim3(1024, 2), 256, 0, stream>>>(Wk, WkH, WkL, Wv, WvH, WvL,
                                                 1048576 / 4);
    cvt_f16_2<<<dim3(512, 2), 256, 0, stream>>>(Em, EB, Dm, DB, 524288 / 4);
    // 2. bias-correction row sums
    rowsum_k<<<256, 256, 0, stream>>>(Em, Dm, sE, sD);
    // 3. Q projection (f16 out)
    gemm_q_f16<<<dim3(128, 8), 256, 0, stream>>>(hsB, WqB, bq, QHq);
    // 4. EH = E @ hs, DH = D @ hs (split-K atomics, merged launch)
    hipMemsetAsync(EHf, 0, 2 * 512 * 1024 * sizeof(float), stream);
    eproj2<<<dim3(8, 8, 8), 256, 0, stream>>>(EB, DB, hsB, EHf, DHf);
    // 5. pk = EH @ Wk^T + sE*bk ; pv = DH @ Wv^T + sD*bv (merged launch)
    gemm_split2<<<dim3(8, 16, 2), 256, 0, stream>>>(EHf, WkH, WkL, bk, sE, pkf,
                                                    DHf, WvH, WvL, bv, sD, pvf);
    // 6. prep f16 pk hi/lo + pvT
    prep_attn<<<64, 256, 0, stream>>>(pkf, pvf, PKH, PKL, PVT);
    // 7. fused attention
    attn_fused<<<dim3(32, 16, 4), 256, 0, stream>>>(QHq, PKH, PKL, PVT, out);
}

// Round 5
// 173.478 us; speedup vs baseline: 1.5960x; 1.0182x over previous
//
#include <hip/hip_runtime.h>
#include <hip/hip_bf16.h>
#include <stdint.h>

// ---------------------------------------------------------------------------
// Linformer attention, MI355X (gfx950).
// B=4, S=4096, DM=1024, H=16, DH=64, K=128.
//
// Pipeline (pk = (E*hs)*Wk^T + (sum_s E)*bk^T  -- avoids computing K,V):
//   1. convert hs, Wq, E, D -> fp16; Wk, Wv -> fp16 hi/lo pairs
//   2. rowsum(E), rowsum(D) -> sE, sD  (bias-correction terms)
//   3. QH = f16(hs_f16 @ Wq_f16^T + bq)  -- dbuf-prefetch GEMM, counted vmcnt
//   4. EHf = E_f16 @ hs_f16  (split-K atomics, E and D in one launch)
//   5. pkf/pvf = split(EHf/DHf) @ (Wh,Wl)^T + s*b  (64x64 tiles, 256 blocks)
//   6. prep_attn: pkf -> PKH/PKL f16; pvf -> PVT f16 [bh][d][k]
//   7. attn: one block = (b,h, 4 q-tiles). Stage pk hi/lo + pvT ONCE
//      (gload_lds, XOR-swizzled), then barrier-free tile loop with Q-prefetch:
//      2-term scores, wave-local softmax, per-wave P half-buffer, PV, store.
// ---------------------------------------------------------------------------

typedef __attribute__((ext_vector_type(8))) _Float16 f16x8;   // 4 VGPR
typedef __attribute__((ext_vector_type(4))) _Float16 f16x4;
typedef __attribute__((ext_vector_type(4))) float    f32x4;

__device__ __forceinline__ f32x4 mfma16(f16x8 a, f16x8 b, f32x4 c) {
    return __builtin_amdgcn_mfma_f32_16x16x32_f16(a, b, c, 0, 0, 0);
}

// async global->LDS, 16B per lane; LDS dest = wave-uniform base + lane*16
__device__ __forceinline__ void gload16(const void* g, void* l) {
    __builtin_amdgcn_global_load_lds(
        (const __attribute__((address_space(1))) void*)g,
        (__attribute__((address_space(3))) void*)l, 16, 0, 0);
}

// ---------------------------------------------------------------- converts --
__global__ __launch_bounds__(256) void cvt_f16(const float* __restrict__ in,
                                               _Float16* __restrict__ out, int n4) {
    int i = blockIdx.x * 256 + threadIdx.x;
    int stride = gridDim.x * 256;
    for (; i < n4; i += stride) {
        f32x4 v = reinterpret_cast<const f32x4*>(in)[i];
        f16x4 o;
#pragma unroll
        for (int j = 0; j < 4; ++j) o[j] = (_Float16)v[j];
        reinterpret_cast<f16x4*>(out)[i] = o;
    }
}

__global__ __launch_bounds__(256) void cvt_f16_2(const float* __restrict__ in0,
                                                 _Float16* __restrict__ out0,
                                                 const float* __restrict__ in1,
                                                 _Float16* __restrict__ out1, int n4) {
    const float* in = blockIdx.y ? in1 : in0;
    _Float16* out = blockIdx.y ? out1 : out0;
    int i = blockIdx.x * 256 + threadIdx.x;
    int stride = gridDim.x * 256;
    for (; i < n4; i += stride) {
        f32x4 v = reinterpret_cast<const f32x4*>(in)[i];
        f16x4 o;
#pragma unroll
        for (int j = 0; j < 4; ++j) o[j] = (_Float16)v[j];
        reinterpret_cast<f16x4*>(out)[i] = o;
    }
}

__global__ __launch_bounds__(256) void cvt_hilo2(const float* __restrict__ in0,
                                                 _Float16* __restrict__ hi0,
                                                 _Float16* __restrict__ lo0,
                                                 const float* __restrict__ in1,
                                                 _Float16* __restrict__ hi1,
                                                 _Float16* __restrict__ lo1, int n4) {
    const float* in = blockIdx.y ? in1 : in0;
    _Float16* hi = blockIdx.y ? hi1 : hi0;
    _Float16* lo = blockIdx.y ? lo1 : lo0;
    int i = blockIdx.x * 256 + threadIdx.x;
    int stride = gridDim.x * 256;
    for (; i < n4; i += stride) {
        f32x4 v = reinterpret_cast<const f32x4*>(in)[i];
        f16x4 h, l;
#pragma unroll
        for (int j = 0; j < 4; ++j) {
            _Float16 hb = (_Float16)v[j];
            h[j] = hb;
            l[j] = (_Float16)(v[j] - (float)hb);
        }
        reinterpret_cast<f16x4*>(hi)[i] = h;
        reinterpret_cast<f16x4*>(lo)[i] = l;
    }
}

// rowsum over S=4096 for E and D: blocks 0..127 -> E rows, 128..255 -> D rows
__global__ __launch_bounds__(256) void rowsum_k(const float* __restrict__ E,
                                                const float* __restrict__ D,
                                                float* __restrict__ sE,
                                                float* __restrict__ sD) {
    __shared__ float red[256];
    const int blk = blockIdx.x;
    const float* src = (blk < 128) ? E : D;
    float* dst = (blk < 128) ? sE : sD;
    const int row = blk & 127;
    float s = 0.f;
    for (int i = threadIdx.x; i < 4096; i += 256) s += src[(size_t)row * 4096 + i];
    red[threadIdx.x] = s;
    __syncthreads();
    for (int off = 128; off > 0; off >>= 1) {
        if ((int)threadIdx.x < off) red[threadIdx.x] += red[threadIdx.x + off];
        __syncthreads();
    }
    if (threadIdx.x == 0) dst[row] = red[0];
}

// --------------------------------------------------- Q projection (f16 out) --
// QH[M,N] f16 = f16(A[M,K]f16 * B[N,K]f16^T + bias[N]).  128x128 tile, BK=64,
// double-buffered LDS, prefetch with counted vmcnt (never 0 mid-loop).
__global__ __launch_bounds__(256) void gemm_q_f16(
    const _Float16* __restrict__ A, const _Float16* __restrict__ B,
    const float* __restrict__ bias, _Float16* __restrict__ Q) {
    const int Kd = 1024, N = 1024, NT = 16;     // K-steps of 64
    __shared__ _Float16 Asm[2][128 * 64];
    __shared__ _Float16 Bsm[2][128 * 64];
    const int tid = threadIdx.x, lane = tid & 63, wave = tid >> 6;
    const int l15 = lane & 15, lg = lane >> 4;
    const int row0 = blockIdx.x * 128, col0 = blockIdx.y * 128;
    const int wr = (wave >> 1) * 64, wc = (wave & 1) * 64;
    f32x4 acc[4][4];
#pragma unroll
    for (int m = 0; m < 4; ++m)
#pragma unroll
        for (int n = 0; n < 4; ++n) acc[m][n] = (f32x4)0.0f;

    // hoisted per-lane source pointers (swizzled chunk) + LDS slot bases
    const _Float16* aSrc[4];
    const _Float16* bSrc[4];
    int ub[4];
#pragma unroll
    for (int it = 0; it < 4; ++it) {
        int u = it * 256 + tid;
        int r = u >> 3, c = u & 7;
        int sc = (c ^ (r & 7)) * 8;
        aSrc[it] = A + (size_t)(row0 + r) * Kd + sc;
        bSrc[it] = B + (size_t)(col0 + r) * Kd + sc;
        ub[it] = it * 256 + wave * 64;
    }
    auto stage = [&](int buf, int t) {
        const int k0 = t * 64;
#pragma unroll
        for (int it = 0; it < 4; ++it) {
            gload16(aSrc[it] + k0, &Asm[buf][ub[it] * 8]);
            gload16(bSrc[it] + k0, &Bsm[buf][ub[it] * 8]);
        }
    };

    stage(0, 0);
#pragma unroll 1
    for (int t = 0; t < NT; ++t) {
        const int cur = t & 1;
        if (t < NT - 1) {
            stage(cur ^ 1, t + 1);                       // prefetch stays in flight
            asm volatile("s_waitcnt vmcnt(8)" ::: "memory");
        } else {
            asm volatile("s_waitcnt vmcnt(0)" ::: "memory");
        }
        __builtin_amdgcn_s_barrier();                    // buf[cur] ready
#pragma unroll
        for (int kk = 0; kk < 2; ++kk) {
            f16x8 af[4], bfr[4];
#pragma unroll
            for (int m = 0; m < 4; ++m)
                af[m] = *reinterpret_cast<const f16x8*>(
                    &Asm[cur][(wr + m * 16 + l15) * 64 + (((kk * 4 + lg) ^ (l15 & 7)) * 8)]);
#pragma unroll
            for (int n = 0; n < 4; ++n)
                bfr[n] = *reinterpret_cast<const f16x8*>(
                    &Bsm[cur][(wc + n * 16 + l15) * 64 + (((kk * 4 + lg) ^ (l15 & 7)) * 8)]);
#pragma unroll
            for (int m = 0; m < 4; ++m)
#pragma unroll
                for (int n = 0; n < 4; ++n) acc[m][n] = mfma16(af[m], bfr[n], acc[m][n]);
        }
        __builtin_amdgcn_s_barrier();                    // all done reading buf[cur]
    }
#pragma unroll
    for (int m = 0; m < 4; ++m)
#pragma unroll
        for (int n = 0; n < 4; ++n) {
            int colg = col0 + wc + n * 16 + l15;
            float bi = bias[colg];
#pragma unroll
            for (int r = 0; r < 4; ++r) {
                int rowg = row0 + wr + m * 16 + lg * 4 + r;
                Q[(size_t)rowg * N + colg] = (_Float16)(acc[m][n][r] + bi);
            }
        }
}

// -------------------------------------------- E/D @ hs projection (NN GEMM) --
// Of[b*128+kk, n] += sum_s Emat[kk,s]*X[b*4096+s, n]; split-K over blockIdx.x.
// blockIdx.z: 0..3 -> E batches, 4..7 -> D batches.
__global__ __launch_bounds__(256) void eproj2(const _Float16* __restrict__ EB,
                                              const _Float16* __restrict__ DB,
                                              const _Float16* __restrict__ X,
                                              float* __restrict__ EHf,
                                              float* __restrict__ DHf) {
    __shared__ _Float16 Ea[128 * 72];
    __shared__ _Float16 BT[128 * 72];
    const int tid = threadIdx.x, lane = tid & 63, wave = tid >> 6;
    const int l15 = lane & 15, lg = lane >> 4;
    const int sc = blockIdx.x;          // K-chunk 0..7 (512 rows each)
    const int n0 = blockIdx.y * 128;
    const int bb = blockIdx.z & 3;
    const _Float16* Emat = (blockIdx.z >> 2) ? DB : EB;
    float* Of = (blockIdx.z >> 2) ? DHf : EHf;
    const int wr = (wave >> 1) * 64, wc = (wave & 1) * 64;
    const int nb = tid & 31, sb = tid >> 5;
    f32x4 acc[4][4];
#pragma unroll
    for (int m = 0; m < 4; ++m)
#pragma unroll
        for (int n = 0; n < 4; ++n) acc[m][n] = (f32x4)0.0f;

    for (int ks = 0; ks < 512; ks += 64) {
        const int s0 = sc * 512 + ks;
        __syncthreads();
#pragma unroll
        for (int i = 0; i < 4; ++i) {  // A tile: E [128 kk][64 s]
            int u = tid + 256 * i;
            int r = u >> 3, c8 = (u & 7) * 8;
            *reinterpret_cast<f16x8*>(&Ea[r * 72 + c8]) =
                *reinterpret_cast<const f16x8*>(Emat + (size_t)r * 4096 + s0 + c8);
        }
        {   // B tile: X [64 s][128 n] -> transposed BT[n][s]
            f16x4 rr[8];
#pragma unroll
            for (int i = 0; i < 8; ++i)
                rr[i] = *reinterpret_cast<const f16x4*>(
                    X + (size_t)(bb * 4096 + s0 + sb * 8 + i) * 1024 + n0 + nb * 4);
#pragma unroll
            for (int j = 0; j < 4; ++j) {
                f16x8 w;
#pragma unroll
                for (int i = 0; i < 8; ++i) w[i] = rr[i][j];
                *reinterpret_cast<f16x8*>(&BT[(nb * 4 + j) * 72 + sb * 8]) = w;
            }
        }
        __syncthreads();
#pragma unroll
        for (int kk = 0; kk < 2; ++kk) {
            f16x8 af[4], bfr[4];
#pragma unroll
            for (int m = 0; m < 4; ++m)
                af[m] = *reinterpret_cast<const f16x8*>(
                    &Ea[(wr + m * 16 + l15) * 72 + kk * 32 + lg * 8]);
#pragma unroll
            for (int n = 0; n < 4; ++n)
                bfr[n] = *reinterpret_cast<const f16x8*>(
                    &BT[(wc + n * 16 + l15) * 72 + kk * 32 + lg * 8]);
#pragma unroll
            for (int m = 0; m < 4; ++m)
#pragma unroll
                for (int n = 0; n < 4; ++n) acc[m][n] = mfma16(af[m], bfr[n], acc[m][n]);
        }
    }
#pragma unroll
    for (int m = 0; m < 4; ++m)
#pragma unroll
        for (int n = 0; n < 4; ++n)
#pragma unroll
            for (int r = 0; r < 4; ++r)
                atomicAdd(&Of[(size_t)(bb * 128 + wr + m * 16 + lg * 4 + r) * 1024 +
                              n0 + wc + n * 16 + l15],
                          acc[m][n][r]);
}

// ----------------------------- split-precision NT GEMM (pk / pv, tiny M) --
// C f32 = split(A f32) @ (Bh+Bl)^T + rowscale[row%128]*bias[col].  BK=32,
// 64x64 tile -> grid (8,16,2) = 256 blocks (full CU coverage).
__global__ __launch_bounds__(256) void gemm_split2(
    const float* __restrict__ A0, const _Float16* __restrict__ Bh0,
    const _Float16* __restrict__ Bl0, const float* __restrict__ bias0,
    const float* __restrict__ rs0, float* __restrict__ C0,
    const float* __restrict__ A1, const _Float16* __restrict__ Bh1,
    const _Float16* __restrict__ Bl1, const float* __restrict__ bias1,
    const float* __restrict__ rs1, float* __restrict__ C1) {
    const int Kd = 1024, N = 1024;
    const float* A = blockIdx.z ? A1 : A0;
    const _Float16* Bh = blockIdx.z ? Bh1 : Bh0;
    const _Float16* Bl = blockIdx.z ? Bl1 : Bl0;
    const float* bias = blockIdx.z ? bias1 : bias0;
    const float* rowscale = blockIdx.z ? rs1 : rs0;
    float* C = blockIdx.z ? C1 : C0;
    __shared__ _Float16 Ah[64 * 40], Al[64 * 40], Bhs[64 * 40], Bls[64 * 40];
    const int tid = threadIdx.x, lane = tid & 63, wave = tid >> 6;
    const int l15 = lane & 15, lg = lane >> 4;
    const int row0 = blockIdx.x * 64, col0 = blockIdx.y * 64;
    const int wr = (wave >> 1) * 32, wc = (wave & 1) * 32;
    f32x4 acc[2][2];
#pragma unroll
    for (int m = 0; m < 2; ++m)
#pragma unroll
        for (int n = 0; n < 2; ++n) acc[m][n] = (f32x4)0.0f;

    const int r = tid >> 2, c8 = (tid & 3) * 8;
    for (int k0 = 0; k0 < Kd; k0 += 32) {
        __syncthreads();
        {   // A: 64 rows x 32 k f32 -> hi/lo f16
            const float* src = A + (size_t)(row0 + r) * Kd + k0 + c8;
            f32x4 v0 = *reinterpret_cast<const f32x4*>(src);
            f32x4 v1 = *reinterpret_cast<const f32x4*>(src + 4);
            f16x8 h8, l8;
#pragma unroll
            for (int j = 0; j < 4; ++j) {
                _Float16 hb = (_Float16)v0[j];
                h8[j] = hb; l8[j] = (_Float16)(v0[j] - (float)hb);
            }
#pragma unroll
            for (int j = 0; j < 4; ++j) {
                _Float16 hb = (_Float16)v1[j];
                h8[4 + j] = hb; l8[4 + j] = (_Float16)(v1[j] - (float)hb);
            }
            *reinterpret_cast<f16x8*>(&Ah[r * 40 + c8]) = h8;
            *reinterpret_cast<f16x8*>(&Al[r * 40 + c8]) = l8;
            // B: 64 rows x 32 k, precomputed hi/lo
            *reinterpret_cast<f16x8*>(&Bhs[r * 40 + c8]) =
                *reinterpret_cast<const f16x8*>(Bh + (size_t)(col0 + r) * Kd + k0 + c8);
            *reinterpret_cast<f16x8*>(&Bls[r * 40 + c8]) =
                *reinterpret_cast<const f16x8*>(Bl + (size_t)(col0 + r) * Kd + k0 + c8);
        }
        __syncthreads();
        f16x8 ah[2], al[2], bh[2], bl[2];
#pragma unroll
        for (int m = 0; m < 2; ++m) {
            ah[m] = *reinterpret_cast<const f16x8*>(&Ah[(wr + m * 16 + l15) * 40 + lg * 8]);
            al[m] = *reinterpret_cast<const f16x8*>(&Al[(wr + m * 16 + l15) * 40 + lg * 8]);
        }
#pragma unroll
        for (int n = 0; n < 2; ++n) {
            bh[n] = *reinterpret_cast<const f16x8*>(&Bhs[(wc + n * 16 + l15) * 40 + lg * 8]);
            bl[n] = *reinterpret_cast<const f16x8*>(&Bls[(wc + n * 16 + l15) * 40 + lg * 8]);
        }
#pragma unroll
        for (int m = 0; m < 2; ++m)
#pragma unroll
            for (int n = 0; n < 2; ++n) {
                acc[m][n] = mfma16(ah[m], bh[n], acc[m][n]);
                acc[m][n] = mfma16(al[m], bh[n], acc[m][n]);
                acc[m][n] = mfma16(ah[m], bl[n], acc[m][n]);
            }
    }
#pragma unroll
    for (int m = 0; m < 2; ++m)
#pragma unroll
        for (int n = 0; n < 2; ++n) {
            int colg = col0 + wc + n * 16 + l15;
            float bi = bias[colg];
#pragma unroll
            for (int rr2 = 0; rr2 < 4; ++rr2) {
                int rowg = row0 + wr + m * 16 + lg * 4 + rr2;
                C[(size_t)rowg * N + colg] = acc[m][n][rr2] + rowscale[rowg & 127] * bi;
            }
        }
}

// --------------------------------------------- prep: pk->hi/lo, pv->pvT f16 --
// grid 64 = (b,h).  PKH/PKL keep the [512][1024] layout; PVT is [bh][64][128].
__global__ __launch_bounds__(256) void prep_attn(
    const float* __restrict__ pkf, const float* __restrict__ pvf,
    _Float16* __restrict__ PKH, _Float16* __restrict__ PKL,
    _Float16* __restrict__ PVT) {
    __shared__ _Float16 tr[64 * 136];
    const int bh = blockIdx.x, bb = bh >> 4, h = bh & 15;
    const int tid = threadIdx.x;
    const int rr = tid >> 4, c4 = (tid & 15) * 4;
#pragma unroll
    for (int p = 0; p < 8; ++p) {
        int k = p * 16 + rr;
        size_t idx = (size_t)(bb * 128 + k) * 1024 + h * 64 + c4;
        f32x4 v = *reinterpret_cast<const f32x4*>(pkf + idx);
        f16x4 hi, lo;
#pragma unroll
        for (int j = 0; j < 4; ++j) {
            _Float16 hb = (_Float16)v[j];
            hi[j] = hb; lo[j] = (_Float16)(v[j] - (float)hb);
        }
        *reinterpret_cast<f16x4*>(PKH + idx) = hi;
        *reinterpret_cast<f16x4*>(PKL + idx) = lo;
        f32x4 w = *reinterpret_cast<const f32x4*>(
            pvf + (size_t)(bb * 128 + k) * 1024 + h * 64 + c4);
#pragma unroll
        for (int j = 0; j < 4; ++j) tr[(c4 + j) * 136 + k] = (_Float16)w[j];
    }
    __syncthreads();
#pragma unroll
    for (int p = 0; p < 4; ++p) {
        int u = p * 256 + tid;
        int d = u >> 4, c = (u & 15) * 8;
        f16x8 w = *reinterpret_cast<const f16x8*>(&tr[d * 136 + c]);
        *reinterpret_cast<f16x8*>(PVT + (size_t)bh * 8192 + d * 128 + c) = w;
    }
}

// ------------------------------------------------------- fused attention --
// One block = (b, h, 4 q-tiles of 128 rows). LDS (64 KiB): pkh 16K | pkl 16K |
// pvt 16K | P 4 waves x [32][64] f16 (16K). Stage once, then barrier-free
// tile loop with depth-1 Q prefetch; waves fully decoupled.
__global__ __launch_bounds__(256) void attn_fused(
    const _Float16* __restrict__ QH, const _Float16* __restrict__ PKH,
    const _Float16* __restrict__ PKL, const _Float16* __restrict__ PVT,
    float* __restrict__ Out) {
    __shared__ _Float16 smem[32768];          // 64 KiB
    const int tid = threadIdx.x, lane = tid & 63, wave = tid >> 6;
    const int l15 = lane & 15, lg = lane >> 4;
    const int sg = blockIdx.x, h = blockIdx.y, bb = blockIdx.z;

    // ---- stage pk hi/lo + pvT once (async DMA, XOR-swizzled sources)
    {
        const _Float16* pkh_g = PKH + (size_t)(bb * 128) * 1024 + h * 64;
        const _Float16* pkl_g = PKL + (size_t)(bb * 128) * 1024 + h * 64;
        const _Float16* pvt_g = PVT + (size_t)(bb * 16 + h) * 8192;
        const int su = wave * 64 + lane;
#pragma unroll
        for (int it = 0; it < 4; ++it) {
            int u = it * 256 + su;
            int ub = it * 256 + wave * 64;
            {
                int r = u >> 3, c = u & 7;
                int sc = (c ^ (r & 7)) * 8;
                gload16(pkh_g + (size_t)r * 1024 + sc, &smem[ub * 8]);
                gload16(pkl_g + (size_t)r * 1024 + sc, &smem[8192 + ub * 8]);
            }
            {
                int r = u >> 4, c = u & 15;
                int sc = (c ^ (r & 7)) * 8;
                gload16(pvt_g + r * 128 + sc, &smem[16384 + ub * 8]);
            }
        }
    }
    _Float16* pw = smem + 24576 + wave * 2048;   // per-wave P half [32][64]

    // ---- preload Q for tile 0 (overlaps the LDS DMA)
    const size_t qbase =
        (size_t)(bb * 4096 + sg * 512 + wave * 32) * 1024 + h * 64;
    f16x8 qc[2][2], qn[2][2];
#pragma unroll
    for (int m = 0; m < 2; ++m)
#pragma unroll
        for (int kk = 0; kk < 2; ++kk)
            qc[m][kk] = *reinterpret_cast<const f16x8*>(
                QH + qbase + (size_t)(m * 16 + l15) * 1024 + kk * 32 + lg * 8);
    __syncthreads();   // drains vmcnt: all LDS tiles resident. Last barrier.

#pragma unroll
    for (int t = 0; t < 4; ++t) {
        // prefetch next tile's Q (stays in flight through this tile's compute)
        if (t < 3) {
            const size_t qb = qbase + (size_t)(t + 1) * 128 * 1024;
#pragma unroll
            for (int m = 0; m < 2; ++m)
#pragma unroll
                for (int kk = 0; kk < 2; ++kk)
                    qn[m][kk] = *reinterpret_cast<const f16x8*>(
                        QH + qb + (size_t)(m * 16 + l15) * 1024 + kk * 32 + lg * 8);
        }

        // ---- scores (2-term: qh*pkh + qh*pkl), K=64
        f32x4 acc[2][8];
#pragma unroll
        for (int m = 0; m < 2; ++m)
#pragma unroll
            for (int n = 0; n < 8; ++n) acc[m][n] = (f32x4)0.0f;
#pragma unroll
        for (int kk = 0; kk < 2; ++kk)
#pragma unroll
            for (int n = 0; n < 8; ++n) {
                int ro = (n * 16 + l15) * 64 + (((kk * 4 + lg) ^ (l15 & 7)) * 8);
                f16x8 bh = *reinterpret_cast<const f16x8*>(&smem[ro]);
                f16x8 bl = *reinterpret_cast<const f16x8*>(&smem[8192 + ro]);
#pragma unroll
                for (int m = 0; m < 2; ++m) {
                    acc[m][n] = mfma16(qc[m][kk], bh, acc[m][n]);
                    acc[m][n] = mfma16(qc[m][kk], bl, acc[m][n]);
                }
            }

        // ---- softmax over 128 cols (8 frags x 16 lanes), deferred 1/denom
        float mx[2][4], inv[2][4];
#pragma unroll
        for (int m = 0; m < 2; ++m)
#pragma unroll
            for (int r = 0; r < 4; ++r) {
                float v = -1e30f;
#pragma unroll
                for (int n = 0; n < 8; ++n) v = fmaxf(v, acc[m][n][r]);
#pragma unroll
                for (int msk = 1; msk < 16; msk <<= 1) v = fmaxf(v, __shfl_xor(v, msk));
                mx[m][r] = v * 0.125f;
            }
#pragma unroll
        for (int m = 0; m < 2; ++m)
#pragma unroll
            for (int n = 0; n < 8; ++n)
#pragma unroll
                for (int r = 0; r < 4; ++r)
                    acc[m][n][r] = __expf(acc[m][n][r] * 0.125f - mx[m][r]);
#pragma unroll
        for (int m = 0; m < 2; ++m)
#pragma unroll
            for (int r = 0; r < 4; ++r) {
                float s = 0.f;
#pragma unroll
                for (int n = 0; n < 8; ++n) s += acc[m][n][r];
#pragma unroll
                for (int msk = 1; msk < 16; msk <<= 1) s += __shfl_xor(s, msk);
                inv[m][r] = 1.0f / s;
            }

        // ---- PV in two 64-col halves through the per-wave P buffer
        f32x4 o[2][4];
#pragma unroll
        for (int m = 0; m < 2; ++m)
#pragma unroll
            for (int n = 0; n < 4; ++n) o[m][n] = (f32x4)0.0f;
#pragma unroll
        for (int half = 0; half < 2; ++half) {
#pragma unroll
            for (int n4 = 0; n4 < 4; ++n4) {
                int n = half * 4 + n4;
#pragma unroll
                for (int m = 0; m < 2; ++m)
#pragma unroll
                    for (int r = 0; r < 4; ++r) {
                        int row = m * 16 + lg * 4 + r;
                        int col = n4 * 16 + l15;
                        pw[row * 64 + (col ^ ((row & 7) << 3))] =
                            (_Float16)acc[m][n][r];
                    }
            }
            // own-wave write->read ordering via lgkmcnt (compiler-inserted)
#pragma unroll
            for (int ks2 = 0; ks2 < 2; ++ks2) {
                int ks = half * 2 + ks2;
                f16x8 af[2];
#pragma unroll
                for (int m = 0; m < 2; ++m) {
                    int row = m * 16 + l15;
                    af[m] = *reinterpret_cast<const f16x8*>(
                        &pw[row * 64 + (((ks2 * 4 + lg) ^ (row & 7)) * 8)]);
                }
#pragma unroll
                for (int n = 0; n < 4; ++n) {
                    int dd = n * 16 + l15;
                    f16x8 bfr = *reinterpret_cast<const f16x8*>(
                        &smem[16384 + dd * 128 + (((ks * 4 + lg) ^ (dd & 7)) * 8)]);
#pragma unroll
                    for (int m = 0; m < 2; ++m) o[m][n] = mfma16(af[m], bfr, o[m][n]);
                }
            }
        }

        // ---- store ctx
        const int orow0 = bb * 4096 + sg * 512 + t * 128 + wave * 32;
#pragma unroll
        for (int m = 0; m < 2; ++m)
#pragma unroll
            for (int n = 0; n < 4; ++n)
#pragma unroll
                for (int r = 0; r < 4; ++r) {
                    int row = orow0 + m * 16 + lg * 4 + r;
                    Out[(size_t)row * 1024 + h * 64 + n * 16 + l15] =
                        o[m][n][r] * inv[m][r];
                }

        // rotate prefetched Q into current
#pragma unroll
        for (int m = 0; m < 2; ++m)
#pragma unroll
            for (int kk = 0; kk < 2; ++kk) qc[m][kk] = qn[m][kk];
    }
}

// ---------------------------------------------------------------------------
extern "C" void kernel_launch(void* const* d_in, const int* in_sizes, int n_in,
                              void* d_out, int out_size, void* d_ws, size_t ws_size,
                              hipStream_t stream) {
    const float* hs = (const float*)d_in[0];
    const float* Wq = (const float*)d_in[1];
    const float* bq = (const float*)d_in[2];
    const float* Wk = (const float*)d_in[3];
    const float* bk = (const float*)d_in[4];
    const float* Wv = (const float*)d_in[5];
    const float* bv = (const float*)d_in[6];
    const float* Em = (const float*)d_in[7];
    const float* Dm = (const float*)d_in[8];
    float* out = (float*)d_out;
    char* ws = (char*)d_ws;

    // workspace layout (bytes)
    _Float16* hsB = (_Float16*)(ws + 0);                  // 33,554,432
    _Float16* WqB = (_Float16*)(ws + 33554432);           //  2,097,152
    _Float16* WkH = (_Float16*)(ws + 35651584);
    _Float16* WkL = (_Float16*)(ws + 37748736);
    _Float16* WvH = (_Float16*)(ws + 39845888);
    _Float16* WvL = (_Float16*)(ws + 41943040);
    _Float16* EB  = (_Float16*)(ws + 44040192);           //  1,048,576
    _Float16* DB  = (_Float16*)(ws + 45088768);
    float* sE  = (float*)(ws + 46137344);                 //        512
    float* sD  = (float*)(ws + 46137856);
    _Float16* QHq = (_Float16*)(ws + 46138368);           // 33,554,432 (f16 Q)
    float* EHf = (float*)(ws + 113247232);                //  2,097,152
    float* DHf = (float*)(ws + 115344384);
    float* pkf = (float*)(ws + 117441536);
    float* pvf = (float*)(ws + 119538688);
    _Float16* PKH = (_Float16*)(ws + 121635840);          //  1,048,576
    _Float16* PKL = (_Float16*)(ws + 122684416);
    _Float16* PVT = (_Float16*)(ws + 123732992);          // end 124,781,568

    // 1. dtype converts
    cvt_f16<<<2048, 256, 0, stream>>>(hs, hsB, 16777216 / 4);
    cvt_f16<<<1024, 256, 0, stream>>>(Wq, WqB, 1048576 / 4);
    cvt_hilo2<<<dim3(1024, 2), 256, 0, stream>>>(Wk, WkH, WkL, Wv, WvH, WvL,
                                                 1048576 / 4);
    cvt_f16_2<<<dim3(512, 2), 256, 0, stream>>>(Em, EB, Dm, DB, 524288 / 4);
    // 2. bias-correction row sums
    rowsum_k<<<256, 256, 0, stream>>>(Em, Dm, sE, sD);
    // 3. Q projection (f16 out)
    gemm_q_f16<<<dim3(128, 8), 256, 0, stream>>>(hsB, WqB, bq, QHq);
    // 4. EH = E @ hs, DH = D @ hs (split-K atomics, merged launch)
    hipMemsetAsync(EHf, 0, 2 * 512 * 1024 * sizeof(float), stream);
    eproj2<<<dim3(8, 8, 8), 256, 0, stream>>>(EB, DB, hsB, EHf, DHf);
    // 5. pk = EH @ Wk^T + sE*bk ; pv = DH @ Wv^T + sD*bv (merged launch)
    gemm_split2<<<dim3(8, 16, 2), 256, 0, stream>>>(EHf, WkH, WkL, bk, sE, pkf,
                                                    DHf, WvH, WvL, bv, sD, pvf);
    // 6. prep f16 pk hi/lo + pvT
    prep_attn<<<64, 256, 0, stream>>>(pkf, pvf, PKH, PKL, PVT);
    // 7. fused attention (block = b,h,4 tiles; barrier-free tile loop)
    attn_fused<<<dim3(8, 16, 4), 256, 0, stream>>>(QHq, PKH, PKL, PVT, out);
}

// Round 6
// 165.985 us; speedup vs baseline: 1.6681x; 1.0451x over previous
//
#include <hip/hip_runtime.h>
#include <hip/hip_bf16.h>
#include <stdint.h>

// ---------------------------------------------------------------------------
// Linformer attention, MI355X (gfx950).
// B=4, S=4096, DM=1024, H=16, DH=64, K=128.
//
// Pipeline (pk = (E*hs)*Wk^T + (sum_s E)*bk^T  -- avoids computing K,V):
//   1. convert hs, Wq, E, D -> fp16; Wk, Wv -> fp16 hi/lo pairs
//   2. rowsum(E), rowsum(D) -> sE, sD  (bias-correction terms)
//   3. QH = f16(hs_f16 @ Wq_f16^T + bq)  -- dbuf-prefetch GEMM, counted vmcnt
//   4. EHf = E_f16 @ hs_f16  (split-K atomics, E and D in one launch)
//   5. PKH = f16((split(EHf)@Wk^T + sE*bk)/8)  [512][1024]   (64x64 tiles)
//      PVT = f16( split(DHf)@Wv^T + sD*bv )    [bh][64 d][128 k] transposed
//   6. attn (2048 blocks, 1 tile each): stage pkh+pvt via gload_lds (XOR-swz),
//      swapped QK^T (S^T = pk.q^T) -> in-lane softmax (31 ops + 2 shfl),
//      P (scaled by 1/denom) -> per-wave LDS half (b64 swizzled, aliases pkh),
//      PV, store.  Occupancy 4 blocks/CU.
// ---------------------------------------------------------------------------

typedef __attribute__((ext_vector_type(8))) _Float16 f16x8;   // 4 VGPR
typedef __attribute__((ext_vector_type(4))) _Float16 f16x4;
typedef __attribute__((ext_vector_type(4))) float    f32x4;

__device__ __forceinline__ f32x4 mfma16(f16x8 a, f16x8 b, f32x4 c) {
    return __builtin_amdgcn_mfma_f32_16x16x32_f16(a, b, c, 0, 0, 0);
}

// async global->LDS, 16B per lane; LDS dest = wave-uniform base + lane*16
__device__ __forceinline__ void gload16(const void* g, void* l) {
    __builtin_amdgcn_global_load_lds(
        (const __attribute__((address_space(1))) void*)g,
        (__attribute__((address_space(3))) void*)l, 16, 0, 0);
}

// ---------------------------------------------------------------- converts --
__global__ __launch_bounds__(256) void cvt_f16(const float* __restrict__ in,
                                               _Float16* __restrict__ out, int n4) {
    int i = blockIdx.x * 256 + threadIdx.x;
    int stride = gridDim.x * 256;
    for (; i < n4; i += stride) {
        f32x4 v = reinterpret_cast<const f32x4*>(in)[i];
        f16x4 o;
#pragma unroll
        for (int j = 0; j < 4; ++j) o[j] = (_Float16)v[j];
        reinterpret_cast<f16x4*>(out)[i] = o;
    }
}

__global__ __launch_bounds__(256) void cvt_f16_2(const float* __restrict__ in0,
                                                 _Float16* __restrict__ out0,
                                                 const float* __restrict__ in1,
                                                 _Float16* __restrict__ out1, int n4) {
    const float* in = blockIdx.y ? in1 : in0;
    _Float16* out = blockIdx.y ? out1 : out0;
    int i = blockIdx.x * 256 + threadIdx.x;
    int stride = gridDim.x * 256;
    for (; i < n4; i += stride) {
        f32x4 v = reinterpret_cast<const f32x4*>(in)[i];
        f16x4 o;
#pragma unroll
        for (int j = 0; j < 4; ++j) o[j] = (_Float16)v[j];
        reinterpret_cast<f16x4*>(out)[i] = o;
    }
}

__global__ __launch_bounds__(256) void cvt_hilo2(const float* __restrict__ in0,
                                                 _Float16* __restrict__ hi0,
                                                 _Float16* __restrict__ lo0,
                                                 const float* __restrict__ in1,
                                                 _Float16* __restrict__ hi1,
                                                 _Float16* __restrict__ lo1, int n4) {
    const float* in = blockIdx.y ? in1 : in0;
    _Float16* hi = blockIdx.y ? hi1 : hi0;
    _Float16* lo = blockIdx.y ? lo1 : lo0;
    int i = blockIdx.x * 256 + threadIdx.x;
    int stride = gridDim.x * 256;
    for (; i < n4; i += stride) {
        f32x4 v = reinterpret_cast<const f32x4*>(in)[i];
        f16x4 h, l;
#pragma unroll
        for (int j = 0; j < 4; ++j) {
            _Float16 hb = (_Float16)v[j];
            h[j] = hb;
            l[j] = (_Float16)(v[j] - (float)hb);
        }
        reinterpret_cast<f16x4*>(hi)[i] = h;
        reinterpret_cast<f16x4*>(lo)[i] = l;
    }
}

// rowsum over S=4096 for E and D: blocks 0..127 -> E rows, 128..255 -> D rows
__global__ __launch_bounds__(256) void rowsum_k(const float* __restrict__ E,
                                                const float* __restrict__ D,
                                                float* __restrict__ sE,
                                                float* __restrict__ sD) {
    __shared__ float red[256];
    const int blk = blockIdx.x;
    const float* src = (blk < 128) ? E : D;
    float* dst = (blk < 128) ? sE : sD;
    const int row = blk & 127;
    float s = 0.f;
    for (int i = threadIdx.x; i < 4096; i += 256) s += src[(size_t)row * 4096 + i];
    red[threadIdx.x] = s;
    __syncthreads();
    for (int off = 128; off > 0; off >>= 1) {
        if ((int)threadIdx.x < off) red[threadIdx.x] += red[threadIdx.x + off];
        __syncthreads();
    }
    if (threadIdx.x == 0) dst[row] = red[0];
}

// --------------------------------------------------- Q projection (f16 out) --
// QH[M,N] f16 = f16(A[M,K]f16 * B[N,K]f16^T + bias[N]).  128x128 tile, BK=64,
// double-buffered LDS, prefetch with counted vmcnt (never 0 mid-loop).
__global__ __launch_bounds__(256) void gemm_q_f16(
    const _Float16* __restrict__ A, const _Float16* __restrict__ B,
    const float* __restrict__ bias, _Float16* __restrict__ Q) {
    const int Kd = 1024, N = 1024, NT = 16;     // K-steps of 64
    __shared__ _Float16 Asm[2][128 * 64];
    __shared__ _Float16 Bsm[2][128 * 64];
    const int tid = threadIdx.x, lane = tid & 63, wave = tid >> 6;
    const int l15 = lane & 15, lg = lane >> 4;
    const int row0 = blockIdx.x * 128, col0 = blockIdx.y * 128;
    const int wr = (wave >> 1) * 64, wc = (wave & 1) * 64;
    f32x4 acc[4][4];
#pragma unroll
    for (int m = 0; m < 4; ++m)
#pragma unroll
        for (int n = 0; n < 4; ++n) acc[m][n] = (f32x4)0.0f;

    // hoisted per-lane source pointers (swizzled chunk) + LDS slot bases
    const _Float16* aSrc[4];
    const _Float16* bSrc[4];
    int ub[4];
#pragma unroll
    for (int it = 0; it < 4; ++it) {
        int u = it * 256 + tid;
        int r = u >> 3, c = u & 7;
        int sc = (c ^ (r & 7)) * 8;
        aSrc[it] = A + (size_t)(row0 + r) * Kd + sc;
        bSrc[it] = B + (size_t)(col0 + r) * Kd + sc;
        ub[it] = it * 256 + wave * 64;
    }
    auto stage = [&](int buf, int t) {
        const int k0 = t * 64;
#pragma unroll
        for (int it = 0; it < 4; ++it) {
            gload16(aSrc[it] + k0, &Asm[buf][ub[it] * 8]);
            gload16(bSrc[it] + k0, &Bsm[buf][ub[it] * 8]);
        }
    };

    stage(0, 0);
#pragma unroll 1
    for (int t = 0; t < NT; ++t) {
        const int cur = t & 1;
        if (t < NT - 1) {
            stage(cur ^ 1, t + 1);                       // prefetch stays in flight
            asm volatile("s_waitcnt vmcnt(8)" ::: "memory");
        } else {
            asm volatile("s_waitcnt vmcnt(0)" ::: "memory");
        }
        __builtin_amdgcn_s_barrier();                    // buf[cur] ready
#pragma unroll
        for (int kk = 0; kk < 2; ++kk) {
            f16x8 af[4], bfr[4];
#pragma unroll
            for (int m = 0; m < 4; ++m)
                af[m] = *reinterpret_cast<const f16x8*>(
                    &Asm[cur][(wr + m * 16 + l15) * 64 + (((kk * 4 + lg) ^ (l15 & 7)) * 8)]);
#pragma unroll
            for (int n = 0; n < 4; ++n)
                bfr[n] = *reinterpret_cast<const f16x8*>(
                    &Bsm[cur][(wc + n * 16 + l15) * 64 + (((kk * 4 + lg) ^ (l15 & 7)) * 8)]);
#pragma unroll
            for (int m = 0; m < 4; ++m)
#pragma unroll
                for (int n = 0; n < 4; ++n) acc[m][n] = mfma16(af[m], bfr[n], acc[m][n]);
        }
        __builtin_amdgcn_s_barrier();                    // all done reading buf[cur]
    }
#pragma unroll
    for (int m = 0; m < 4; ++m)
#pragma unroll
        for (int n = 0; n < 4; ++n) {
            int colg = col0 + wc + n * 16 + l15;
            float bi = bias[colg];
#pragma unroll
            for (int r = 0; r < 4; ++r) {
                int rowg = row0 + wr + m * 16 + lg * 4 + r;
                Q[(size_t)rowg * N + colg] = (_Float16)(acc[m][n][r] + bi);
            }
        }
}

// -------------------------------------------- E/D @ hs projection (NN GEMM) --
// Of[b*128+kk, n] += sum_s Emat[kk,s]*X[b*4096+s, n]; split-K over blockIdx.x.
// blockIdx.z: 0..3 -> E batches, 4..7 -> D batches.
__global__ __launch_bounds__(256) void eproj2(const _Float16* __restrict__ EB,
                                              const _Float16* __restrict__ DB,
                                              const _Float16* __restrict__ X,
                                              float* __restrict__ EHf,
                                              float* __restrict__ DHf) {
    __shared__ _Float16 Ea[128 * 72];
    __shared__ _Float16 BT[128 * 72];
    const int tid = threadIdx.x, lane = tid & 63, wave = tid >> 6;
    const int l15 = lane & 15, lg = lane >> 4;
    const int sc = blockIdx.x;          // K-chunk 0..7 (512 rows each)
    const int n0 = blockIdx.y * 128;
    const int bb = blockIdx.z & 3;
    const _Float16* Emat = (blockIdx.z >> 2) ? DB : EB;
    float* Of = (blockIdx.z >> 2) ? DHf : EHf;
    const int wr = (wave >> 1) * 64, wc = (wave & 1) * 64;
    const int nb = tid & 31, sb = tid >> 5;
    f32x4 acc[4][4];
#pragma unroll
    for (int m = 0; m < 4; ++m)
#pragma unroll
        for (int n = 0; n < 4; ++n) acc[m][n] = (f32x4)0.0f;

    for (int ks = 0; ks < 512; ks += 64) {
        const int s0 = sc * 512 + ks;
        __syncthreads();
#pragma unroll
        for (int i = 0; i < 4; ++i) {  // A tile: E [128 kk][64 s]
            int u = tid + 256 * i;
            int r = u >> 3, c8 = (u & 7) * 8;
            *reinterpret_cast<f16x8*>(&Ea[r * 72 + c8]) =
                *reinterpret_cast<const f16x8*>(Emat + (size_t)r * 4096 + s0 + c8);
        }
        {   // B tile: X [64 s][128 n] -> transposed BT[n][s]
            f16x4 rr[8];
#pragma unroll
            for (int i = 0; i < 8; ++i)
                rr[i] = *reinterpret_cast<const f16x4*>(
                    X + (size_t)(bb * 4096 + s0 + sb * 8 + i) * 1024 + n0 + nb * 4);
#pragma unroll
            for (int j = 0; j < 4; ++j) {
                f16x8 w;
#pragma unroll
                for (int i = 0; i < 8; ++i) w[i] = rr[i][j];
                *reinterpret_cast<f16x8*>(&BT[(nb * 4 + j) * 72 + sb * 8]) = w;
            }
        }
        __syncthreads();
#pragma unroll
        for (int kk = 0; kk < 2; ++kk) {
            f16x8 af[4], bfr[4];
#pragma unroll
            for (int m = 0; m < 4; ++m)
                af[m] = *reinterpret_cast<const f16x8*>(
                    &Ea[(wr + m * 16 + l15) * 72 + kk * 32 + lg * 8]);
#pragma unroll
            for (int n = 0; n < 4; ++n)
                bfr[n] = *reinterpret_cast<const f16x8*>(
                    &BT[(wc + n * 16 + l15) * 72 + kk * 32 + lg * 8]);
#pragma unroll
            for (int m = 0; m < 4; ++m)
#pragma unroll
                for (int n = 0; n < 4; ++n) acc[m][n] = mfma16(af[m], bfr[n], acc[m][n]);
        }
    }
#pragma unroll
    for (int m = 0; m < 4; ++m)
#pragma unroll
        for (int n = 0; n < 4; ++n)
#pragma unroll
            for (int r = 0; r < 4; ++r)
                atomicAdd(&Of[(size_t)(bb * 128 + wr + m * 16 + lg * 4 + r) * 1024 +
                              n0 + wc + n * 16 + l15],
                          acc[m][n][r]);
}

// ------------- split-precision NT GEMM -> PKH (scaled f16) / PVT (transposed) --
// acc = split(A f32) @ (Bh+Bl)^T + rowscale[row%128]*bias[col].  BK=32,
// 64x64 tile, grid (8,16,2).  z=0: PKH[rowg][colg] = f16(acc/8).
// z=1: PVT[(rowg>>7)*16+(colg>>6)][colg&63][rowg&127] = f16(acc).
__global__ __launch_bounds__(256) void gemm_split2(
    const float* __restrict__ A0, const _Float16* __restrict__ Bh0,
    const _Float16* __restrict__ Bl0, const float* __restrict__ bias0,
    const float* __restrict__ rs0, _Float16* __restrict__ PKH,
    const float* __restrict__ A1, const _Float16* __restrict__ Bh1,
    const _Float16* __restrict__ Bl1, const float* __restrict__ bias1,
    const float* __restrict__ rs1, _Float16* __restrict__ PVT) {
    const int Kd = 1024;
    const float* A = blockIdx.z ? A1 : A0;
    const _Float16* Bh = blockIdx.z ? Bh1 : Bh0;
    const _Float16* Bl = blockIdx.z ? Bl1 : Bl0;
    const float* bias = blockIdx.z ? bias1 : bias0;
    const float* rowscale = blockIdx.z ? rs1 : rs0;
    __shared__ _Float16 Ah[64 * 40], Al[64 * 40], Bhs[64 * 40], Bls[64 * 40];
    const int tid = threadIdx.x, lane = tid & 63, wave = tid >> 6;
    const int l15 = lane & 15, lg = lane >> 4;
    const int row0 = blockIdx.x * 64, col0 = blockIdx.y * 64;
    const int wr = (wave >> 1) * 32, wc = (wave & 1) * 32;
    f32x4 acc[2][2];
#pragma unroll
    for (int m = 0; m < 2; ++m)
#pragma unroll
        for (int n = 0; n < 2; ++n) acc[m][n] = (f32x4)0.0f;

    const int r = tid >> 2, c8 = (tid & 3) * 8;
    for (int k0 = 0; k0 < Kd; k0 += 32) {
        __syncthreads();
        {   // A: 64 rows x 32 k f32 -> hi/lo f16
            const float* src = A + (size_t)(row0 + r) * Kd + k0 + c8;
            f32x4 v0 = *reinterpret_cast<const f32x4*>(src);
            f32x4 v1 = *reinterpret_cast<const f32x4*>(src + 4);
            f16x8 h8, l8;
#pragma unroll
            for (int j = 0; j < 4; ++j) {
                _Float16 hb = (_Float16)v0[j];
                h8[j] = hb; l8[j] = (_Float16)(v0[j] - (float)hb);
            }
#pragma unroll
            for (int j = 0; j < 4; ++j) {
                _Float16 hb = (_Float16)v1[j];
                h8[4 + j] = hb; l8[4 + j] = (_Float16)(v1[j] - (float)hb);
            }
            *reinterpret_cast<f16x8*>(&Ah[r * 40 + c8]) = h8;
            *reinterpret_cast<f16x8*>(&Al[r * 40 + c8]) = l8;
            *reinterpret_cast<f16x8*>(&Bhs[r * 40 + c8]) =
                *reinterpret_cast<const f16x8*>(Bh + (size_t)(col0 + r) * Kd + k0 + c8);
            *reinterpret_cast<f16x8*>(&Bls[r * 40 + c8]) =
                *reinterpret_cast<const f16x8*>(Bl + (size_t)(col0 + r) * Kd + k0 + c8);
        }
        __syncthreads();
        f16x8 ah[2], al[2], bh[2], bl[2];
#pragma unroll
        for (int m = 0; m < 2; ++m) {
            ah[m] = *reinterpret_cast<const f16x8*>(&Ah[(wr + m * 16 + l15) * 40 + lg * 8]);
            al[m] = *reinterpret_cast<const f16x8*>(&Al[(wr + m * 16 + l15) * 40 + lg * 8]);
        }
#pragma unroll
        for (int n = 0; n < 2; ++n) {
            bh[n] = *reinterpret_cast<const f16x8*>(&Bhs[(wc + n * 16 + l15) * 40 + lg * 8]);
            bl[n] = *reinterpret_cast<const f16x8*>(&Bls[(wc + n * 16 + l15) * 40 + lg * 8]);
        }
#pragma unroll
        for (int m = 0; m < 2; ++m)
#pragma unroll
            for (int n = 0; n < 2; ++n) {
                acc[m][n] = mfma16(ah[m], bh[n], acc[m][n]);
                acc[m][n] = mfma16(al[m], bh[n], acc[m][n]);
                acc[m][n] = mfma16(ah[m], bl[n], acc[m][n]);
            }
    }
#pragma unroll
    for (int m = 0; m < 2; ++m)
#pragma unroll
        for (int n = 0; n < 2; ++n) {
            int colg = col0 + wc + n * 16 + l15;
            float bi = bias[colg];
#pragma unroll
            for (int rr2 = 0; rr2 < 4; ++rr2) {
                int rowg = row0 + wr + m * 16 + lg * 4 + rr2;
                float val = acc[m][n][rr2] + rowscale[rowg & 127] * bi;
                if (blockIdx.z == 0) {
                    PKH[(size_t)rowg * 1024 + colg] = (_Float16)(val * 0.125f);
                } else {
                    PVT[(size_t)((rowg >> 7) * 16 + (colg >> 6)) * 8192 +
                        (colg & 63) * 128 + (rowg & 127)] = (_Float16)val;
                }
            }
        }
}

// ------------------------------------------------------- fused attention --
// Per block: (st, h, b) -> 128 q-rows, 4 waves x 32 rows. LDS 32 KiB:
// pkh [128][64] (16K, pre-scaled by 1/8) | pvt [64][128] (16K); P aliases pkh
// (4 KB/wave, two 64-k halves).  Swapped QK^T: accT[n][m] holds
// P[q=l15+16m][k=n*16+lg*4+r] -> in-lane softmax, b64 swizzled P writes.
__global__ __launch_bounds__(256, 4) void attn_fused(
    const _Float16* __restrict__ QH, const _Float16* __restrict__ PKH,
    const _Float16* __restrict__ PVT, float* __restrict__ Out) {
    __shared__ _Float16 smem[16384];          // 32 KiB
    const int tid = threadIdx.x, lane = tid & 63, wave = tid >> 6;
    const int l15 = lane & 15, lg = lane >> 4;
    const int st = blockIdx.x, h = blockIdx.y, bb = blockIdx.z;

    // ---- async stage pkh ([128][64]) and pvt ([64][128]), XOR-swizzled src
    {
        const _Float16* pkh_g = PKH + (size_t)(bb * 128) * 1024 + h * 64;
        const _Float16* pvt_g = PVT + (size_t)(bb * 16 + h) * 8192;
        const int su = wave * 64 + lane;
#pragma unroll
        for (int it = 0; it < 4; ++it) {
            int u = it * 256 + su;
            int ub = it * 256 + wave * 64;
            {
                int r = u >> 3, c = u & 7;
                int sc = (c ^ (r & 7)) * 8;
                gload16(pkh_g + (size_t)r * 1024 + sc, &smem[ub * 8]);
            }
            {
                int r = u >> 4, c = u & 15;
                int sc = (c ^ (r & 7)) * 8;
                gload16(pvt_g + r * 128 + sc, &smem[8192 + ub * 8]);
            }
        }
    }
    // ---- q fragments (overlap the DMA): B-operand, rows = q
    const int srow0 = bb * 4096 + st * 128 + wave * 32;
    f16x8 qf[2][2];
#pragma unroll
    for (int m = 0; m < 2; ++m)
#pragma unroll
        for (int kk = 0; kk < 2; ++kk)
            qf[m][kk] = *reinterpret_cast<const f16x8*>(
                QH + (size_t)(srow0 + m * 16 + l15) * 1024 + h * 64 + kk * 32 + lg * 8);
    __syncthreads();   // drains vmcnt: LDS tiles resident

    // ---- swapped scores: accT[n][m] = pk_frag . q_frag  (S^T layout)
    f32x4 accT[8][2];
#pragma unroll
    for (int n = 0; n < 8; ++n)
#pragma unroll
        for (int m = 0; m < 2; ++m) accT[n][m] = (f32x4)0.0f;
#pragma unroll
    for (int kk = 0; kk < 2; ++kk)
#pragma unroll
        for (int n = 0; n < 8; ++n) {
            f16x8 pk = *reinterpret_cast<const f16x8*>(
                &smem[(n * 16 + l15) * 64 + (((kk * 4 + lg) ^ (l15 & 7)) * 8)]);
#pragma unroll
            for (int m = 0; m < 2; ++m)
                accT[n][m] = mfma16(pk, qf[m][kk], accT[n][m]);
        }
    __syncthreads();   // all waves done reading pkh: safe to alias P over it

    // ---- softmax: lane holds 32 of 128 k for q-row (l15+16m); scale by inv
#pragma unroll
    for (int m = 0; m < 2; ++m) {
        float v = -1e30f;
#pragma unroll
        for (int n = 0; n < 8; ++n)
#pragma unroll
            for (int r = 0; r < 4; ++r) v = fmaxf(v, accT[n][m][r]);
        v = fmaxf(v, __shfl_xor(v, 16));
        v = fmaxf(v, __shfl_xor(v, 32));
        float s = 0.f;
#pragma unroll
        for (int n = 0; n < 8; ++n)
#pragma unroll
            for (int r = 0; r < 4; ++r) {
                float e = __expf(accT[n][m][r] - v);
                accT[n][m][r] = e;
                s += e;
            }
        s += __shfl_xor(s, 16);
        s += __shfl_xor(s, 32);
        float inv = 1.0f / s;
#pragma unroll
        for (int n = 0; n < 8; ++n)
#pragma unroll
            for (int r = 0; r < 4; ++r) accT[n][m][r] *= inv;
    }

    // ---- PV through per-wave P half-buffer (aliases pkh region)
    _Float16* pw = smem + wave * 2048;           // [32 q][64 k] f16, swizzled
    f32x4 o[2][4];
#pragma unroll
    for (int m = 0; m < 2; ++m)
#pragma unroll
        for (int n = 0; n < 4; ++n) o[m][n] = (f32x4)0.0f;
#pragma unroll
    for (int half = 0; half < 2; ++half) {
        // write P half: 8 x ds_write_b64, swizzled (kpair ^= (q&7)<<2)
#pragma unroll
        for (int nl = 0; nl < 4; ++nl) {
            int n = half * 4 + nl;
#pragma unroll
            for (int m = 0; m < 2; ++m) {
                int q = l15 + 16 * m;
                int kp = (nl * 8 + lg * 2) ^ ((q & 7) << 2);
                f16x4 v;
#pragma unroll
                for (int r = 0; r < 4; ++r) v[r] = (_Float16)accT[n][m][r];
                *reinterpret_cast<f16x4*>(&pw[q * 64 + kp * 2]) = v;
            }
        }
        // own-wave write->read ordering via lgkmcnt (compiler-inserted)
#pragma unroll
        for (int ksl = 0; ksl < 2; ++ksl) {
            f16x8 pa[2];
#pragma unroll
            for (int m = 0; m < 2; ++m) {
                int q = m * 16 + l15;
                int kpb = (ksl * 16 + lg * 4) ^ ((q & 7) << 2);
                pa[m] = *reinterpret_cast<const f16x8*>(&pw[q * 64 + kpb * 2]);
            }
            int ks = half * 2 + ksl;
#pragma unroll
            for (int n = 0; n < 4; ++n) {
                int dd = n * 16 + l15;
                f16x8 bv = *reinterpret_cast<const f16x8*>(
                    &smem[8192 + dd * 128 + (((ks * 4 + lg) ^ (dd & 7)) * 8)]);
#pragma unroll
                for (int m = 0; m < 2; ++m) o[m][n] = mfma16(pa[m], bv, o[m][n]);
            }
        }
    }

    // ---- store ctx (inv already folded into P)
#pragma unroll
    for (int m = 0; m < 2; ++m)
#pragma unroll
        for (int n = 0; n < 4; ++n)
#pragma unroll
            for (int r = 0; r < 4; ++r) {
                int row = srow0 + m * 16 + lg * 4 + r;
                Out[(size_t)row * 1024 + h * 64 + n * 16 + l15] = o[m][n][r];
            }
}

// ---------------------------------------------------------------------------
extern "C" void kernel_launch(void* const* d_in, const int* in_sizes, int n_in,
                              void* d_out, int out_size, void* d_ws, size_t ws_size,
                              hipStream_t stream) {
    const float* hs = (const float*)d_in[0];
    const float* Wq = (const float*)d_in[1];
    const float* bq = (const float*)d_in[2];
    const float* Wk = (const float*)d_in[3];
    const float* bk = (const float*)d_in[4];
    const float* Wv = (const float*)d_in[5];
    const float* bv = (const float*)d_in[6];
    const float* Em = (const float*)d_in[7];
    const float* Dm = (const float*)d_in[8];
    float* out = (float*)d_out;
    char* ws = (char*)d_ws;

    // workspace layout (bytes)
    _Float16* hsB = (_Float16*)(ws + 0);                  // 33,554,432
    _Float16* WqB = (_Float16*)(ws + 33554432);           //  2,097,152
    _Float16* WkH = (_Float16*)(ws + 35651584);
    _Float16* WkL = (_Float16*)(ws + 37748736);
    _Float16* WvH = (_Float16*)(ws + 39845888);
    _Float16* WvL = (_Float16*)(ws + 41943040);
    _Float16* EB  = (_Float16*)(ws + 44040192);           //  1,048,576
    _Float16* DB  = (_Float16*)(ws + 45088768);
    float* sE  = (float*)(ws + 46137344);                 //        512
    float* sD  = (float*)(ws + 46137856);
    _Float16* QHq = (_Float16*)(ws + 46138368);           // 33,554,432 (f16 Q)
    float* EHf = (float*)(ws + 113247232);                //  2,097,152
    float* DHf = (float*)(ws + 115344384);
    _Float16* PKH = (_Float16*)(ws + 117441536);          //  1,048,576
    _Float16* PVT = (_Float16*)(ws + 118490112);          // end 119,538,688

    // 1. dtype converts
    cvt_f16<<<2048, 256, 0, stream>>>(hs, hsB, 16777216 / 4);
    cvt_f16<<<1024, 256, 0, stream>>>(Wq, WqB, 1048576 / 4);
    cvt_hilo2<<<dim3(1024, 2), 256, 0, stream>>>(Wk, WkH, WkL, Wv, WvH, WvL,
                                                 1048576 / 4);
    cvt_f16_2<<<dim3(512, 2), 256, 0, stream>>>(Em, EB, Dm, DB, 524288 / 4);
    // 2. bias-correction row sums
    rowsum_k<<<256, 256, 0, stream>>>(Em, Dm, sE, sD);
    // 3. Q projection (f16 out)
    gemm_q_f16<<<dim3(128, 8), 256, 0, stream>>>(hsB, WqB, bq, QHq);
    // 4. EH = E @ hs, DH = D @ hs (split-K atomics, merged launch)
    hipMemsetAsync(EHf, 0, 2 * 512 * 1024 * sizeof(float), stream);
    eproj2<<<dim3(8, 8, 8), 256, 0, stream>>>(EB, DB, hsB, EHf, DHf);
    // 5. PKH = f16((EH@Wk^T + sE*bk)/8) ; PVT = f16(DH@Wv^T + sD*bv)^T
    gemm_split2<<<dim3(8, 16, 2), 256, 0, stream>>>(EHf, WkH, WkL, bk, sE, PKH,
                                                    DHf, WvH, WvL, bv, sD, PVT);
    // 6. fused attention
    attn_fused<<<dim3(32, 16, 4), 256, 0, stream>>>(QHq, PKH, PVT, out);
}

// Round 7
// 163.973 us; speedup vs baseline: 1.6885x; 1.0123x over previous
//
#include <hip/hip_runtime.h>
#include <hip/hip_bf16.h>
#include <stdint.h>

// ---------------------------------------------------------------------------
// Linformer attention, MI355X (gfx950).
// B=4, S=4096, DM=1024, H=16, DH=64, K=128.
//
// Pipeline (pk = (E*hs)*Wk^T + (sum_s E)*bk^T  -- avoids computing K,V):
//   1. convert hs, Wq, E, D -> fp16; Wk, Wv -> fp16 hi/lo pairs
//   2. rowsum(E), rowsum(D) -> sE, sD  (bias-correction terms)
//   3. QH = f16(hs @ Wq^T + bq) -- 256x256-tile 8-wave dbuf GEMM, counted vmcnt
//   4. EHf = E_f16 @ hs_f16  (split-K atomics, E and D in one launch)
//   5. PKH = f16((split(EHf)@Wk^T + sE*bk)/8)  [512][1024]   (64x64 tiles)
//      PVT = f16( split(DHf)@Wv^T + sD*bv )    [bh][64 d][128 k] transposed
//   6. attn (2048 blocks, 1 tile each): stage pkh+pvt via gload_lds (XOR-swz),
//      swapped QK^T (S^T = pk.q^T) -> in-lane softmax (31 ops + 2 shfl),
//      P (scaled by 1/denom) -> per-wave LDS half (b64 swizzled, aliases pkh),
//      PV, store.  Occupancy 4 blocks/CU.
// ---------------------------------------------------------------------------

typedef __attribute__((ext_vector_type(8))) _Float16 f16x8;   // 4 VGPR
typedef __attribute__((ext_vector_type(4))) _Float16 f16x4;
typedef __attribute__((ext_vector_type(4))) float    f32x4;

__device__ __forceinline__ f32x4 mfma16(f16x8 a, f16x8 b, f32x4 c) {
    return __builtin_amdgcn_mfma_f32_16x16x32_f16(a, b, c, 0, 0, 0);
}

// async global->LDS, 16B per lane; LDS dest = wave-uniform base + lane*16
__device__ __forceinline__ void gload16(const void* g, void* l) {
    __builtin_amdgcn_global_load_lds(
        (const __attribute__((address_space(1))) void*)g,
        (__attribute__((address_space(3))) void*)l, 16, 0, 0);
}

// ---------------------------------------------------------------- converts --
__global__ __launch_bounds__(256) void cvt_f16(const float* __restrict__ in,
                                               _Float16* __restrict__ out, int n4) {
    int i = blockIdx.x * 256 + threadIdx.x;
    int stride = gridDim.x * 256;
    for (; i < n4; i += stride) {
        f32x4 v = reinterpret_cast<const f32x4*>(in)[i];
        f16x4 o;
#pragma unroll
        for (int j = 0; j < 4; ++j) o[j] = (_Float16)v[j];
        reinterpret_cast<f16x4*>(out)[i] = o;
    }
}

__global__ __launch_bounds__(256) void cvt_f16_2(const float* __restrict__ in0,
                                                 _Float16* __restrict__ out0,
                                                 const float* __restrict__ in1,
                                                 _Float16* __restrict__ out1, int n4) {
    const float* in = blockIdx.y ? in1 : in0;
    _Float16* out = blockIdx.y ? out1 : out0;
    int i = blockIdx.x * 256 + threadIdx.x;
    int stride = gridDim.x * 256;
    for (; i < n4; i += stride) {
        f32x4 v = reinterpret_cast<const f32x4*>(in)[i];
        f16x4 o;
#pragma unroll
        for (int j = 0; j < 4; ++j) o[j] = (_Float16)v[j];
        reinterpret_cast<f16x4*>(out)[i] = o;
    }
}

__global__ __launch_bounds__(256) void cvt_hilo2(const float* __restrict__ in0,
                                                 _Float16* __restrict__ hi0,
                                                 _Float16* __restrict__ lo0,
                                                 const float* __restrict__ in1,
                                                 _Float16* __restrict__ hi1,
                                                 _Float16* __restrict__ lo1, int n4) {
    const float* in = blockIdx.y ? in1 : in0;
    _Float16* hi = blockIdx.y ? hi1 : hi0;
    _Float16* lo = blockIdx.y ? lo1 : lo0;
    int i = blockIdx.x * 256 + threadIdx.x;
    int stride = gridDim.x * 256;
    for (; i < n4; i += stride) {
        f32x4 v = reinterpret_cast<const f32x4*>(in)[i];
        f16x4 h, l;
#pragma unroll
        for (int j = 0; j < 4; ++j) {
            _Float16 hb = (_Float16)v[j];
            h[j] = hb;
            l[j] = (_Float16)(v[j] - (float)hb);
        }
        reinterpret_cast<f16x4*>(hi)[i] = h;
        reinterpret_cast<f16x4*>(lo)[i] = l;
    }
}

// rowsum over S=4096 for E and D: blocks 0..127 -> E rows, 128..255 -> D rows
__global__ __launch_bounds__(256) void rowsum_k(const float* __restrict__ E,
                                                const float* __restrict__ D,
                                                float* __restrict__ sE,
                                                float* __restrict__ sD) {
    __shared__ float red[256];
    const int blk = blockIdx.x;
    const float* src = (blk < 128) ? E : D;
    float* dst = (blk < 128) ? sE : sD;
    const int row = blk & 127;
    float s = 0.f;
    for (int i = threadIdx.x; i < 4096; i += 256) s += src[(size_t)row * 4096 + i];
    red[threadIdx.x] = s;
    __syncthreads();
    for (int off = 128; off > 0; off >>= 1) {
        if ((int)threadIdx.x < off) red[threadIdx.x] += red[threadIdx.x + off];
        __syncthreads();
    }
    if (threadIdx.x == 0) dst[row] = red[0];
}

// --------------------------------------------------- Q projection (f16 out) --
// QH[M,N] f16 = f16(A[M,K]f16 * B[N,K]f16^T + bias[N]).  256x256 tile, BK=64,
// 8 waves (512 thr), 128 KiB double-buffered LDS, counted vmcnt prefetch.
// Per wave: 128x64 output = acc[8][4] f32x4; MFMA:ds_read = 64:24 per K-step.
__global__ __launch_bounds__(512) void gemm_q_f16(
    const _Float16* __restrict__ A, const _Float16* __restrict__ B,
    const float* __restrict__ bias, _Float16* __restrict__ Q) {
    const int Kd = 1024, N = 1024, NT = 16;     // K-steps of 64
    __shared__ _Float16 Asm[2][256 * 64];       // 64 KiB
    __shared__ _Float16 Bsm[2][256 * 64];       // 64 KiB
    const int tid = threadIdx.x, lane = tid & 63, wave = tid >> 6;
    const int l15 = lane & 15, lg = lane >> 4;
    const int row0 = blockIdx.x * 256, col0 = blockIdx.y * 256;
    const int wr = (wave >> 2) * 128, wc = (wave & 3) * 64;
    f32x4 acc[8][4];
#pragma unroll
    for (int m = 0; m < 8; ++m)
#pragma unroll
        for (int n = 0; n < 4; ++n) acc[m][n] = (f32x4)0.0f;

    // staging: tile [256 rows][64 k] = 2048 chunks of 16B; 4 rounds x 512 thr.
    // slot u=(r,c) holds swizzled source chunk c^(r&7); LDS stays linear.
    const _Float16* aSrc[4];
    const _Float16* bSrc[4];
    int ub[4];
#pragma unroll
    for (int it = 0; it < 4; ++it) {
        int u = it * 512 + tid;
        int r = u >> 3, c = u & 7;
        int sc = (c ^ (r & 7)) * 8;
        aSrc[it] = A + (size_t)(row0 + r) * Kd + sc;
        bSrc[it] = B + (size_t)(col0 + r) * Kd + sc;
        ub[it] = it * 512 + wave * 64;
    }
    auto stage = [&](int buf, int t) {
        const int k0 = t * 64;
#pragma unroll
        for (int it = 0; it < 4; ++it)
            gload16(aSrc[it] + k0, &Asm[buf][ub[it] * 8]);
#pragma unroll
        for (int it = 0; it < 4; ++it)
            gload16(bSrc[it] + k0, &Bsm[buf][ub[it] * 8]);
    };

    stage(0, 0);
#pragma unroll 1
    for (int t = 0; t < NT; ++t) {
        const int cur = t & 1;
        if (t < NT - 1) {
            stage(cur ^ 1, t + 1);                       // prefetch stays in flight
            asm volatile("s_waitcnt vmcnt(8)" ::: "memory");
        } else {
            asm volatile("s_waitcnt vmcnt(0)" ::: "memory");
        }
        __builtin_amdgcn_s_barrier();                    // buf[cur] ready
#pragma unroll
        for (int kk = 0; kk < 2; ++kk) {
            const int ksw = ((kk * 4 + lg) ^ (l15 & 7)) * 8;
            f16x8 af[8], bfr[4];
#pragma unroll
            for (int m = 0; m < 8; ++m)
                af[m] = *reinterpret_cast<const f16x8*>(
                    &Asm[cur][(wr + m * 16 + l15) * 64 + ksw]);
#pragma unroll
            for (int n = 0; n < 4; ++n)
                bfr[n] = *reinterpret_cast<const f16x8*>(
                    &Bsm[cur][(wc + n * 16 + l15) * 64 + ksw]);
#pragma unroll
            for (int m = 0; m < 8; ++m)
#pragma unroll
                for (int n = 0; n < 4; ++n) acc[m][n] = mfma16(af[m], bfr[n], acc[m][n]);
        }
        __builtin_amdgcn_s_barrier();                    // all done reading buf[cur]
    }
#pragma unroll
    for (int m = 0; m < 8; ++m)
#pragma unroll
        for (int n = 0; n < 4; ++n) {
            int colg = col0 + wc + n * 16 + l15;
            float bi = bias[colg];
#pragma unroll
            for (int r = 0; r < 4; ++r) {
                int rowg = row0 + wr + m * 16 + lg * 4 + r;
                Q[(size_t)rowg * N + colg] = (_Float16)(acc[m][n][r] + bi);
            }
        }
}

// -------------------------------------------- E/D @ hs projection (NN GEMM) --
// Of[b*128+kk, n] += sum_s Emat[kk,s]*X[b*4096+s, n]; split-K over blockIdx.x.
// blockIdx.z: 0..3 -> E batches, 4..7 -> D batches.
__global__ __launch_bounds__(256) void eproj2(const _Float16* __restrict__ EB,
                                              const _Float16* __restrict__ DB,
                                              const _Float16* __restrict__ X,
                                              float* __restrict__ EHf,
                                              float* __restrict__ DHf) {
    __shared__ _Float16 Ea[128 * 72];
    __shared__ _Float16 BT[128 * 72];
    const int tid = threadIdx.x, lane = tid & 63, wave = tid >> 6;
    const int l15 = lane & 15, lg = lane >> 4;
    const int sc = blockIdx.x;          // K-chunk 0..7 (512 rows each)
    const int n0 = blockIdx.y * 128;
    const int bb = blockIdx.z & 3;
    const _Float16* Emat = (blockIdx.z >> 2) ? DB : EB;
    float* Of = (blockIdx.z >> 2) ? DHf : EHf;
    const int wr = (wave >> 1) * 64, wc = (wave & 1) * 64;
    const int nb = tid & 31, sb = tid >> 5;
    f32x4 acc[4][4];
#pragma unroll
    for (int m = 0; m < 4; ++m)
#pragma unroll
        for (int n = 0; n < 4; ++n) acc[m][n] = (f32x4)0.0f;

    for (int ks = 0; ks < 512; ks += 64) {
        const int s0 = sc * 512 + ks;
        __syncthreads();
#pragma unroll
        for (int i = 0; i < 4; ++i) {  // A tile: E [128 kk][64 s]
            int u = tid + 256 * i;
            int r = u >> 3, c8 = (u & 7) * 8;
            *reinterpret_cast<f16x8*>(&Ea[r * 72 + c8]) =
                *reinterpret_cast<const f16x8*>(Emat + (size_t)r * 4096 + s0 + c8);
        }
        {   // B tile: X [64 s][128 n] -> transposed BT[n][s]
            f16x4 rr[8];
#pragma unroll
            for (int i = 0; i < 8; ++i)
                rr[i] = *reinterpret_cast<const f16x4*>(
                    X + (size_t)(bb * 4096 + s0 + sb * 8 + i) * 1024 + n0 + nb * 4);
#pragma unroll
            for (int j = 0; j < 4; ++j) {
                f16x8 w;
#pragma unroll
                for (int i = 0; i < 8; ++i) w[i] = rr[i][j];
                *reinterpret_cast<f16x8*>(&BT[(nb * 4 + j) * 72 + sb * 8]) = w;
            }
        }
        __syncthreads();
#pragma unroll
        for (int kk = 0; kk < 2; ++kk) {
            f16x8 af[4], bfr[4];
#pragma unroll
            for (int m = 0; m < 4; ++m)
                af[m] = *reinterpret_cast<const f16x8*>(
                    &Ea[(wr + m * 16 + l15) * 72 + kk * 32 + lg * 8]);
#pragma unroll
            for (int n = 0; n < 4; ++n)
                bfr[n] = *reinterpret_cast<const f16x8*>(
                    &BT[(wc + n * 16 + l15) * 72 + kk * 32 + lg * 8]);
#pragma unroll
            for (int m = 0; m < 4; ++m)
#pragma unroll
                for (int n = 0; n < 4; ++n) acc[m][n] = mfma16(af[m], bfr[n], acc[m][n]);
        }
    }
#pragma unroll
    for (int m = 0; m < 4; ++m)
#pragma unroll
        for (int n = 0; n < 4; ++n)
#pragma unroll
            for (int r = 0; r < 4; ++r)
                atomicAdd(&Of[(size_t)(bb * 128 + wr + m * 16 + lg * 4 + r) * 1024 +
                              n0 + wc + n * 16 + l15],
                          acc[m][n][r]);
}

// ------------- split-precision NT GEMM -> PKH (scaled f16) / PVT (transposed) --
// acc = split(A f32) @ (Bh+Bl)^T + rowscale[row%128]*bias[col].  BK=32,
// 64x64 tile, grid (8,16,2).  z=0: PKH[rowg][colg] = f16(acc/8).
// z=1: PVT[(rowg>>7)*16+(colg>>6)][colg&63][rowg&127] = f16(acc).
__global__ __launch_bounds__(256) void gemm_split2(
    const float* __restrict__ A0, const _Float16* __restrict__ Bh0,
    const _Float16* __restrict__ Bl0, const float* __restrict__ bias0,
    const float* __restrict__ rs0, _Float16* __restrict__ PKH,
    const float* __restrict__ A1, const _Float16* __restrict__ Bh1,
    const _Float16* __restrict__ Bl1, const float* __restrict__ bias1,
    const float* __restrict__ rs1, _Float16* __restrict__ PVT) {
    const int Kd = 1024;
    const float* A = blockIdx.z ? A1 : A0;
    const _Float16* Bh = blockIdx.z ? Bh1 : Bh0;
    const _Float16* Bl = blockIdx.z ? Bl1 : Bl0;
    const float* bias = blockIdx.z ? bias1 : bias0;
    const float* rowscale = blockIdx.z ? rs1 : rs0;
    __shared__ _Float16 Ah[64 * 40], Al[64 * 40], Bhs[64 * 40], Bls[64 * 40];
    const int tid = threadIdx.x, lane = tid & 63, wave = tid >> 6;
    const int l15 = lane & 15, lg = lane >> 4;
    const int row0 = blockIdx.x * 64, col0 = blockIdx.y * 64;
    const int wr = (wave >> 1) * 32, wc = (wave & 1) * 32;
    f32x4 acc[2][2];
#pragma unroll
    for (int m = 0; m < 2; ++m)
#pragma unroll
        for (int n = 0; n < 2; ++n) acc[m][n] = (f32x4)0.0f;

    const int r = tid >> 2, c8 = (tid & 3) * 8;
    for (int k0 = 0; k0 < Kd; k0 += 32) {
        __syncthreads();
        {   // A: 64 rows x 32 k f32 -> hi/lo f16
            const float* src = A + (size_t)(row0 + r) * Kd + k0 + c8;
            f32x4 v0 = *reinterpret_cast<const f32x4*>(src);
            f32x4 v1 = *reinterpret_cast<const f32x4*>(src + 4);
            f16x8 h8, l8;
#pragma unroll
            for (int j = 0; j < 4; ++j) {
                _Float16 hb = (_Float16)v0[j];
                h8[j] = hb; l8[j] = (_Float16)(v0[j] - (float)hb);
            }
#pragma unroll
            for (int j = 0; j < 4; ++j) {
                _Float16 hb = (_Float16)v1[j];
                h8[4 + j] = hb; l8[4 + j] = (_Float16)(v1[j] - (float)hb);
            }
            *reinterpret_cast<f16x8*>(&Ah[r * 40 + c8]) = h8;
            *reinterpret_cast<f16x8*>(&Al[r * 40 + c8]) = l8;
            *reinterpret_cast<f16x8*>(&Bhs[r * 40 + c8]) =
                *reinterpret_cast<const f16x8*>(Bh + (size_t)(col0 + r) * Kd + k0 + c8);
            *reinterpret_cast<f16x8*>(&Bls[r * 40 + c8]) =
                *reinterpret_cast<const f16x8*>(Bl + (size_t)(col0 + r) * Kd + k0 + c8);
        }
        __syncthreads();
        f16x8 ah[2], al[2], bh[2], bl[2];
#pragma unroll
        for (int m = 0; m < 2; ++m) {
            ah[m] = *reinterpret_cast<const f16x8*>(&Ah[(wr + m * 16 + l15) * 40 + lg * 8]);
            al[m] = *reinterpret_cast<const f16x8*>(&Al[(wr + m * 16 + l15) * 40 + lg * 8]);
        }
#pragma unroll
        for (int n = 0; n < 2; ++n) {
            bh[n] = *reinterpret_cast<const f16x8*>(&Bhs[(wc + n * 16 + l15) * 40 + lg * 8]);
            bl[n] = *reinterpret_cast<const f16x8*>(&Bls[(wc + n * 16 + l15) * 40 + lg * 8]);
        }
#pragma unroll
        for (int m = 0; m < 2; ++m)
#pragma unroll
            for (int n = 0; n < 2; ++n) {
                acc[m][n] = mfma16(ah[m], bh[n], acc[m][n]);
                acc[m][n] = mfma16(al[m], bh[n], acc[m][n]);
                acc[m][n] = mfma16(ah[m], bl[n], acc[m][n]);
            }
    }
#pragma unroll
    for (int m = 0; m < 2; ++m)
#pragma unroll
        for (int n = 0; n < 2; ++n) {
            int colg = col0 + wc + n * 16 + l15;
            float bi = bias[colg];
#pragma unroll
            for (int rr2 = 0; rr2 < 4; ++rr2) {
                int rowg = row0 + wr + m * 16 + lg * 4 + rr2;
                float val = acc[m][n][rr2] + rowscale[rowg & 127] * bi;
                if (blockIdx.z == 0) {
                    PKH[(size_t)rowg * 1024 + colg] = (_Float16)(val * 0.125f);
                } else {
                    PVT[(size_t)((rowg >> 7) * 16 + (colg >> 6)) * 8192 +
                        (colg & 63) * 128 + (rowg & 127)] = (_Float16)val;
                }
            }
        }
}

// ------------------------------------------------------- fused attention --
// Per block: (st, h, b) -> 128 q-rows, 4 waves x 32 rows. LDS 32 KiB:
// pkh [128][64] (16K, pre-scaled by 1/8) | pvt [64][128] (16K); P aliases pkh
// (4 KB/wave, two 64-k halves).  Swapped QK^T: accT[n][m] holds
// P[q=l15+16m][k=n*16+lg*4+r] -> in-lane softmax, b64 swizzled P writes.
__global__ __launch_bounds__(256, 4) void attn_fused(
    const _Float16* __restrict__ QH, const _Float16* __restrict__ PKH,
    const _Float16* __restrict__ PVT, float* __restrict__ Out) {
    __shared__ _Float16 smem[16384];          // 32 KiB
    const int tid = threadIdx.x, lane = tid & 63, wave = tid >> 6;
    const int l15 = lane & 15, lg = lane >> 4;
    const int st = blockIdx.x, h = blockIdx.y, bb = blockIdx.z;

    // ---- async stage pkh ([128][64]) and pvt ([64][128]), XOR-swizzled src
    {
        const _Float16* pkh_g = PKH + (size_t)(bb * 128) * 1024 + h * 64;
        const _Float16* pvt_g = PVT + (size_t)(bb * 16 + h) * 8192;
        const int su = wave * 64 + lane;
#pragma unroll
        for (int it = 0; it < 4; ++it) {
            int u = it * 256 + su;
            int ub = it * 256 + wave * 64;
            {
                int r = u >> 3, c = u & 7;
                int sc = (c ^ (r & 7)) * 8;
                gload16(pkh_g + (size_t)r * 1024 + sc, &smem[ub * 8]);
            }
            {
                int r = u >> 4, c = u & 15;
                int sc = (c ^ (r & 7)) * 8;
                gload16(pvt_g + r * 128 + sc, &smem[8192 + ub * 8]);
            }
        }
    }
    // ---- q fragments (overlap the DMA): B-operand, rows = q
    const int srow0 = bb * 4096 + st * 128 + wave * 32;
    f16x8 qf[2][2];
#pragma unroll
    for (int m = 0; m < 2; ++m)
#pragma unroll
        for (int kk = 0; kk < 2; ++kk)
            qf[m][kk] = *reinterpret_cast<const f16x8*>(
                QH + (size_t)(srow0 + m * 16 + l15) * 1024 + h * 64 + kk * 32 + lg * 8);
    __syncthreads();   // drains vmcnt: LDS tiles resident

    // ---- swapped scores: accT[n][m] = pk_frag . q_frag  (S^T layout)
    f32x4 accT[8][2];
#pragma unroll
    for (int n = 0; n < 8; ++n)
#pragma unroll
        for (int m = 0; m < 2; ++m) accT[n][m] = (f32x4)0.0f;
#pragma unroll
    for (int kk = 0; kk < 2; ++kk)
#pragma unroll
        for (int n = 0; n < 8; ++n) {
            f16x8 pk = *reinterpret_cast<const f16x8*>(
                &smem[(n * 16 + l15) * 64 + (((kk * 4 + lg) ^ (l15 & 7)) * 8)]);
#pragma unroll
            for (int m = 0; m < 2; ++m)
                accT[n][m] = mfma16(pk, qf[m][kk], accT[n][m]);
        }
    __syncthreads();   // all waves done reading pkh: safe to alias P over it

    // ---- softmax: lane holds 32 of 128 k for q-row (l15+16m); scale by inv
#pragma unroll
    for (int m = 0; m < 2; ++m) {
        float v = -1e30f;
#pragma unroll
        for (int n = 0; n < 8; ++n)
#pragma unroll
            for (int r = 0; r < 4; ++r) v = fmaxf(v, accT[n][m][r]);
        v = fmaxf(v, __shfl_xor(v, 16));
        v = fmaxf(v, __shfl_xor(v, 32));
        float s = 0.f;
#pragma unroll
        for (int n = 0; n < 8; ++n)
#pragma unroll
            for (int r = 0; r < 4; ++r) {
                float e = __expf(accT[n][m][r] - v);
                accT[n][m][r] = e;
                s += e;
            }
        s += __shfl_xor(s, 16);
        s += __shfl_xor(s, 32);
        float inv = 1.0f / s;
#pragma unroll
        for (int n = 0; n < 8; ++n)
#pragma unroll
            for (int r = 0; r < 4; ++r) accT[n][m][r] *= inv;
    }

    // ---- PV through per-wave P half-buffer (aliases pkh region)
    _Float16* pw = smem + wave * 2048;           // [32 q][64 k] f16, swizzled
    f32x4 o[2][4];
#pragma unroll
    for (int m = 0; m < 2; ++m)
#pragma unroll
        for (int n = 0; n < 4; ++n) o[m][n] = (f32x4)0.0f;
#pragma unroll
    for (int half = 0; half < 2; ++half) {
        // write P half: 8 x ds_write_b64, swizzled (kpair ^= (q&7)<<2)
#pragma unroll
        for (int nl = 0; nl < 4; ++nl) {
            int n = half * 4 + nl;
#pragma unroll
            for (int m = 0; m < 2; ++m) {
                int q = l15 + 16 * m;
                int kp = (nl * 8 + lg * 2) ^ ((q & 7) << 2);
                f16x4 v;
#pragma unroll
                for (int r = 0; r < 4; ++r) v[r] = (_Float16)accT[n][m][r];
                *reinterpret_cast<f16x4*>(&pw[q * 64 + kp * 2]) = v;
            }
        }
        // own-wave write->read ordering via lgkmcnt (compiler-inserted)
#pragma unroll
        for (int ksl = 0; ksl < 2; ++ksl) {
            f16x8 pa[2];
#pragma unroll
            for (int m = 0; m < 2; ++m) {
                int q = m * 16 + l15;
                int kpb = (ksl * 16 + lg * 4) ^ ((q & 7) << 2);
                pa[m] = *reinterpret_cast<const f16x8*>(&pw[q * 64 + kpb * 2]);
            }
            int ks = half * 2 + ksl;
#pragma unroll
            for (int n = 0; n < 4; ++n) {
                int dd = n * 16 + l15;
                f16x8 bv = *reinterpret_cast<const f16x8*>(
                    &smem[8192 + dd * 128 + (((ks * 4 + lg) ^ (dd & 7)) * 8)]);
#pragma unroll
                for (int m = 0; m < 2; ++m) o[m][n] = mfma16(pa[m], bv, o[m][n]);
            }
        }
    }

    // ---- store ctx (inv already folded into P)
#pragma unroll
    for (int m = 0; m < 2; ++m)
#pragma unroll
        for (int n = 0; n < 4; ++n)
#pragma unroll
            for (int r = 0; r < 4; ++r) {
                int row = srow0 + m * 16 + lg * 4 + r;
                Out[(size_t)row * 1024 + h * 64 + n * 16 + l15] = o[m][n][r];
            }
}

// ---------------------------------------------------------------------------
extern "C" void kernel_launch(void* const* d_in, const int* in_sizes, int n_in,
                              void* d_out, int out_size, void* d_ws, size_t ws_size,
                              hipStream_t stream) {
    const float* hs = (const float*)d_in[0];
    const float* Wq = (const float*)d_in[1];
    const float* bq = (const float*)d_in[2];
    const float* Wk = (const float*)d_in[3];
    const float* bk = (const float*)d_in[4];
    const float* Wv = (const float*)d_in[5];
    const float* bv = (const float*)d_in[6];
    const float* Em = (const float*)d_in[7];
    const float* Dm = (const float*)d_in[8];
    float* out = (float*)d_out;
    char* ws = (char*)d_ws;

    // workspace layout (bytes)
    _Float16* hsB = (_Float16*)(ws + 0);                  // 33,554,432
    _Float16* WqB = (_Float16*)(ws + 33554432);           //  2,097,152
    _Float16* WkH = (_Float16*)(ws + 35651584);
    _Float16* WkL = (_Float16*)(ws + 37748736);
    _Float16* WvH = (_Float16*)(ws + 39845888);
    _Float16* WvL = (_Float16*)(ws + 41943040);
    _Float16* EB  = (_Float16*)(ws + 44040192);           //  1,048,576
    _Float16* DB  = (_Float16*)(ws + 45088768);
    float* sE  = (float*)(ws + 46137344);                 //        512
    float* sD  = (float*)(ws + 46137856);
    _Float16* QHq = (_Float16*)(ws + 46138368);           // 33,554,432 (f16 Q)
    float* EHf = (float*)(ws + 113247232);                //  2,097,152
    float* DHf = (float*)(ws + 115344384);
    _Float16* PKH = (_Float16*)(ws + 117441536);          //  1,048,576
    _Float16* PVT = (_Float16*)(ws + 118490112);          // end 119,538,688

    // 1. dtype converts
    cvt_f16<<<2048, 256, 0, stream>>>(hs, hsB, 16777216 / 4);
    cvt_f16<<<1024, 256, 0, stream>>>(Wq, WqB, 1048576 / 4);
    cvt_hilo2<<<dim3(1024, 2), 256, 0, stream>>>(Wk, WkH, WkL, Wv, WvH, WvL,
                                                 1048576 / 4);
    cvt_f16_2<<<dim3(512, 2), 256, 0, stream>>>(Em, EB, Dm, DB, 524288 / 4);
    // 2. bias-correction row sums
    rowsum_k<<<256, 256, 0, stream>>>(Em, Dm, sE, sD);
    // 3. Q projection (f16 out; 256x256 tile, 8 waves, 1 block/CU)
    gemm_q_f16<<<dim3(64, 4), 512, 0, stream>>>(hsB, WqB, bq, QHq);
    // 4. EH = E @ hs, DH = D @ hs (split-K atomics, merged launch)
    hipMemsetAsync(EHf, 0, 2 * 512 * 1024 * sizeof(float), stream);
    eproj2<<<dim3(8, 8, 8), 256, 0, stream>>>(EB, DB, hsB, EHf, DHf);
    // 5. PKH = f16((EH@Wk^T + sE*bk)/8) ; PVT = f16(DH@Wv^T + sD*bv)^T
    gemm_split2<<<dim3(8, 16, 2), 256, 0, stream>>>(EHf, WkH, WkL, bk, sE, PKH,
                                                    DHf, WvH, WvL, bv, sD, PVT);
    // 6. fused attention
    attn_fused<<<dim3(32, 16, 4), 256, 0, stream>>>(QHq, PKH, PVT, out);
}